// Round 1
// baseline (4288.971 us; speedup 1.0000x reference)
//
#include <hip/hip_runtime.h>
#include <math.h>

#define NU 100000
#define NI 100000
#define NE 200000
#define NTOT (NU + NI)

// ---------------- degree kernels ----------------
__global__ void deg_count_kernel(const int* __restrict__ idx, float* __restrict__ deg, int E) {
    int t = blockIdx.x * blockDim.x + threadIdx.x;
    if (t < E) atomicAdd(&deg[idx[t]], 1.0f);
}

__global__ void rsqrt_clip_kernel(float* __restrict__ deg, int n) {
    int t = blockIdx.x * blockDim.x + threadIdx.x;
    if (t < n) deg[t] = 1.0f / sqrtf(fmaxf(deg[t], 1.0f));
}

// ---------------- edge scatter: agg[dst] += x[src] * rs_src[src] ----------------
__global__ void scatter_add_kernel(const float* __restrict__ x, const int* __restrict__ src,
                                   const int* __restrict__ dst, const float* __restrict__ rs,
                                   float* __restrict__ agg, int E) {
    int t = blockIdx.x * blockDim.x + threadIdx.x;
    int e = t >> 5;
    if (e >= E) return;
    int lane = t & 31;
    int s = src[e], d = dst[e];
    float sc = rs[s];
    const float4 v = *reinterpret_cast<const float4*>(x + (size_t)s * 128 + lane * 4);
    float* o = agg + (size_t)d * 128 + lane * 4;
    atomicAdd(o + 0, v.x * sc);
    atomicAdd(o + 1, v.y * sc);
    atomicAdd(o + 2, v.z * sc);
    atomicAdd(o + 3, v.w * sc);
}

// ---------------- fp32 tiled GEMM, K=128 fixed ----------------
// C[M x N] = op(A) @ op(B) + bias (+ addend)
//   A: M x 128 row-major.  op(A) row r optionally relu'd and/or scaled by scale[r].
//   B: TRANS_B ? (N x 128, use B^T) : (128 x N)
// BM=64, BN=128, BK=16, 256 threads, each thread 4 rows x 8 cols.
// In-place safe (C == A) when gridDim.x == 1: each block reads all its A rows
// (through LDS, before the last __syncthreads) before writing its C rows.
#define BM 64
#define BN 128
#define BK 16

template <bool TRANS_B, bool RELU_A, bool HAS_SCALE, bool HAS_ADDEND>
__global__ __launch_bounds__(256) void gemm128_kernel(
    const float* __restrict__ A, const float* __restrict__ B,
    const float* __restrict__ bias, const float* __restrict__ scale,
    const float* __restrict__ addend, float* __restrict__ C, int M, int N) {
    __shared__ float As[BM][BK + 4];
    __shared__ float Bs[BK][BN + 4];

    const int tid = threadIdx.x;
    const int row0 = blockIdx.y * BM;
    const int col0 = blockIdx.x * BN;
    const int tx = tid & 15;   // col group
    const int ty = tid >> 4;   // row group

    float acc[4][8];
#pragma unroll
    for (int i = 0; i < 4; i++)
#pragma unroll
        for (int j = 0; j < 8; j++) acc[i][j] = 0.0f;

    for (int k0 = 0; k0 < 128; k0 += BK) {
        // ---- load A tile (64 x 16), one float4 per thread ----
        {
            int r = tid >> 2;             // 0..63
            int c4 = (tid & 3) * 4;       // 0,4,8,12
            int grow = row0 + r;
            float4 v = make_float4(0.f, 0.f, 0.f, 0.f);
            if (grow < M) {
                v = *reinterpret_cast<const float4*>(A + (size_t)grow * 128 + k0 + c4);
                if (RELU_A) {
                    v.x = fmaxf(v.x, 0.f); v.y = fmaxf(v.y, 0.f);
                    v.z = fmaxf(v.z, 0.f); v.w = fmaxf(v.w, 0.f);
                }
                if (HAS_SCALE) {
                    float s = scale[grow];
                    v.x *= s; v.y *= s; v.z *= s; v.w *= s;
                }
            }
            *reinterpret_cast<float4*>(&As[r][c4]) = v;
        }
        // ---- load B tile (16 x 128) ----
        if (!TRANS_B) {
#pragma unroll
            for (int l = 0; l < 2; l++) {
                int idx = tid + l * 256;
                int r = idx >> 5;            // 0..15
                int c4 = (idx & 31) * 4;     // 0..124
                float4 v = *reinterpret_cast<const float4*>(B + (size_t)(k0 + r) * N + col0 + c4);
                *reinterpret_cast<float4*>(&Bs[r][c4]) = v;
            }
        } else {
            // B is (N x 128) row-major; Bs[k][c] = B[(col0+c)*128 + k0 + k]
#pragma unroll
            for (int l = 0; l < 2; l++) {
                int idx = tid + l * 256;
                int c = idx >> 2;            // 0..127
                int r4 = (idx & 3) * 4;      // 0,4,8,12
                float4 v = *reinterpret_cast<const float4*>(B + (size_t)(col0 + c) * 128 + k0 + r4);
                Bs[r4 + 0][c] = v.x;
                Bs[r4 + 1][c] = v.y;
                Bs[r4 + 2][c] = v.z;
                Bs[r4 + 3][c] = v.w;
            }
        }
        __syncthreads();

#pragma unroll
        for (int kk = 0; kk < BK; kk++) {
            float a[4], b[8];
#pragma unroll
            for (int i = 0; i < 4; i++) a[i] = As[ty + 16 * i][kk];
#pragma unroll
            for (int j = 0; j < 8; j++) b[j] = Bs[kk][tx + 16 * j];
#pragma unroll
            for (int i = 0; i < 4; i++)
#pragma unroll
                for (int j = 0; j < 8; j++) acc[i][j] += a[i] * b[j];
        }
        __syncthreads();
    }

    // ---- epilogue ----
#pragma unroll
    for (int i = 0; i < 4; i++) {
        int grow = row0 + ty + 16 * i;
        if (grow >= M) continue;
#pragma unroll
        for (int j = 0; j < 8; j++) {
            int gcol = col0 + tx + 16 * j;
            float v = acc[i][j] + bias[gcol];
            if (HAS_ADDEND) v += addend[(size_t)grow * N + gcol];
            C[(size_t)grow * N + gcol] = v;
        }
    }
}

// ---------------- GRU gates ----------------
__global__ void gru_gates_kernel(const float* __restrict__ gi, const float* __restrict__ gh,
                                 const float* __restrict__ h, float* __restrict__ out, int rows) {
    int idx = blockIdx.x * blockDim.x + threadIdx.x;
    if (idx >= rows * 128) return;
    int r = idx >> 7, c = idx & 127;
    const float* gir = gi + (size_t)r * 384;
    const float* ghr = gh + (size_t)r * 384;
    float ir = gir[c], iz = gir[128 + c], in = gir[256 + c];
    float hr = ghr[c], hz = ghr[128 + c], hn = ghr[256 + c];
    float rr = 1.0f / (1.0f + expf(-(ir + hr)));
    float z  = 1.0f / (1.0f + expf(-(iz + hz)));
    float n  = tanhf(in + rr * hn);
    float hv = h[idx];
    out[idx] = (1.0f - z) * n + z * hv;
}

// ---------------- launch ----------------
extern "C" void kernel_launch(void* const* d_in, const int* in_sizes, int n_in,
                              void* d_out, int out_size, void* d_ws, size_t ws_size,
                              hipStream_t stream) {
    const float* feat_user = (const float*)d_in[0];
    const float* feat_item = (const float*)d_in[1];
    const float* hidden0   = (const float*)d_in[2];

    const int* src_f = (const int*)d_in[3];
    const int* dst_f = (const int*)d_in[4];
    const float* W1f = (const float*)d_in[5];  const float* b1f = (const float*)d_in[6];
    const float* W2f = (const float*)d_in[7];  const float* b2f = (const float*)d_in[8];

    const int* src_b = (const int*)d_in[9];
    const int* dst_b = (const int*)d_in[10];
    const float* W1b = (const float*)d_in[11]; const float* b1b = (const float*)d_in[12];
    const float* W2b = (const float*)d_in[13]; const float* b2b = (const float*)d_in[14];

    const int* src_r = (const int*)d_in[15];
    const int* dst_r = (const int*)d_in[16];
    const float* W1r = (const float*)d_in[17]; const float* b1r = (const float*)d_in[18];
    const float* W2r = (const float*)d_in[19]; const float* b2r = (const float*)d_in[20];

    const int* src_s = (const int*)d_in[21];
    const int* dst_s = (const int*)d_in[22];
    const float* W1s = (const float*)d_in[23]; const float* b1s = (const float*)d_in[24];
    const float* W2s = (const float*)d_in[25]; const float* b2s = (const float*)d_in[26];

    const float* wih = (const float*)d_in[27];
    const float* whh = (const float*)d_in[28];
    const float* bih = (const float*)d_in[29];
    const float* bhh = (const float*)d_in[30];

    // workspace layout
    float* p = (float*)d_ws;
    float* rs_sf = p; p += NU;  // follows: src deg (NU)
    float* rs_df = p; p += NU;  //          dst deg (NU)
    float* rs_sb = p; p += NU;  // buys:    src (NU)
    float* rs_db = p; p += NI;  //          dst (NI)
    float* rs_sr = p; p += NI;  // revbuys: src (NI)
    float* rs_dr = p; p += NU;  //          dst (NU)
    float* rs_ss = p; p += NI;  // similar: src (NI)
    float* rs_ds = p; p += NI;  //          dst (NI)
    float* aggA = p; p += (size_t)NU * 128;
    float* aggB = p; p += (size_t)NU * 128;

    float* outLo = (float*)d_out;                  // rows [0, NU)
    float* outHi = outLo + (size_t)NU * 128;       // rows [NU, NU+NI)

    const size_t AGG_BYTES = (size_t)NU * 128 * sizeof(float);
    const int SC_BLOCKS = (NE * 32 + 255) / 256;

    auto degree = [&](const int* idx, float* rs, int n) {
        hipMemsetAsync(rs, 0, (size_t)n * sizeof(float), stream);
        deg_count_kernel<<<(NE + 255) / 256, 256, 0, stream>>>(idx, rs, NE);
        rsqrt_clip_kernel<<<(n + 255) / 256, 256, 0, stream>>>(rs, n);
    };

    // ---- degrees ----
    degree(src_f, rs_sf, NU); degree(dst_f, rs_df, NU);
    degree(src_b, rs_sb, NU); degree(dst_b, rs_db, NI);
    degree(src_r, rs_sr, NI); degree(dst_r, rs_dr, NU);
    degree(src_s, rs_ss, NI); degree(dst_s, rs_ds, NI);

    auto scatter = [&](const float* x, const int* src, const int* dst, const float* rs, float* agg) {
        scatter_add_kernel<<<SC_BLOCKS, 256, 0, stream>>>(x, src, dst, rs, agg, NE);
    };
    auto gemm_conv = [&](const float* A, const float* W, const float* b, const float* scl,
                         const float* add, float* C, int M) {
        dim3 g(1, (M + BM - 1) / BM);
        if (add)
            gemm128_kernel<false, false, true, true><<<g, 256, 0, stream>>>(A, W, b, scl, add, C, M, 128);
        else
            gemm128_kernel<false, false, true, false><<<g, 256, 0, stream>>>(A, W, b, scl, nullptr, C, M, 128);
    };

    // ---- layer 1 (pre-activation hu/hi into d_out; relu deferred to GRU load) ----
    hipMemsetAsync(aggA, 0, AGG_BYTES, stream);
    scatter(feat_user, src_f, dst_f, rs_sf, aggA);
    gemm_conv(aggA, W1f, b1f, rs_df, nullptr, aggA, NU);          // in-place
    hipMemsetAsync(aggB, 0, AGG_BYTES, stream);
    scatter(feat_item, src_r, dst_r, rs_sr, aggB);
    gemm_conv(aggB, W1r, b1r, rs_dr, aggA, outLo, NU);            // hu_pre

    hipMemsetAsync(aggA, 0, AGG_BYTES, stream);
    scatter(feat_user, src_b, dst_b, rs_sb, aggA);
    gemm_conv(aggA, W1b, b1b, rs_db, nullptr, aggA, NI);          // in-place
    hipMemsetAsync(aggB, 0, AGG_BYTES, stream);
    scatter(feat_item, src_s, dst_s, rs_ss, aggB);
    gemm_conv(aggB, W1s, b1s, rs_ds, aggA, outHi, NI);            // hi_pre

    // ---- GRU (chunked; gi->aggA, gh->aggB; writes hc in place over d_out) ----
    const int RCH = 32768;
    for (int r0 = 0; r0 < NTOT; r0 += RCH) {
        int m = NTOT - r0; if (m > RCH) m = RCH;
        dim3 g(3, (m + BM - 1) / BM);
        gemm128_kernel<true, true, false, false><<<g, 256, 0, stream>>>(
            outLo + (size_t)r0 * 128, wih, bih, nullptr, nullptr, aggA, m, 384);
        gemm128_kernel<true, false, false, false><<<g, 256, 0, stream>>>(
            hidden0 + (size_t)r0 * 128, whh, bhh, nullptr, nullptr, aggB, m, 384);
        gru_gates_kernel<<<(m * 128 + 255) / 256, 256, 0, stream>>>(
            aggA, aggB, hidden0 + (size_t)r0 * 128, outLo + (size_t)r0 * 128, m);
    }

    // ---- layer 2 (hu = outLo, hi = outHi are hc halves) ----
    hipMemsetAsync(aggA, 0, AGG_BYTES, stream);
    scatter(outLo, src_f, dst_f, rs_sf, aggA);
    gemm_conv(aggA, W2f, b2f, rs_df, nullptr, aggA, NU);          // in-place: follows product
    hipMemsetAsync(aggB, 0, AGG_BYTES, stream);
    scatter(outLo, src_b, dst_b, rs_sb, aggB);
    gemm_conv(aggB, W2b, b2b, rs_db, nullptr, aggB, NI);          // in-place: buys product
    // hu (outLo) fully consumed; reuse as agg for revbuys
    hipMemsetAsync(outLo, 0, AGG_BYTES, stream);
    scatter(outHi, src_r, dst_r, rs_sr, outLo);
    gemm_conv(outLo, W2r, b2r, rs_dr, aggA, outLo, NU);           // ou = revbuys + follows
    // hi (outHi) last read here
    hipMemsetAsync(aggA, 0, AGG_BYTES, stream);
    scatter(outHi, src_s, dst_s, rs_ss, aggA);
    gemm_conv(aggA, W2s, b2s, rs_ds, aggB, outHi, NI);            // oi = similar + buys
}

// Round 2
// 1807.022 us; speedup vs baseline: 2.3735x; 2.3735x over previous
//
#include <hip/hip_runtime.h>
#include <math.h>

#define NU 100000
#define NI 100000
#define NE 200000
#define NTOT (NU + NI)
#define NN 100000          // all node sets are 100000
#define NB_SCAN ((NN + 1023) / 1024)   // 98

// ---------------- degree / histogram kernels ----------------
__global__ void deg_count_kernel(const int* __restrict__ idx, float* __restrict__ deg, int E) {
    int t = blockIdx.x * blockDim.x + threadIdx.x;
    if (t < E) atomicAdd(&deg[idx[t]], 1.0f);
}

__global__ void rsqrt_clip_kernel(float* __restrict__ deg, int n) {
    int t = blockIdx.x * blockDim.x + threadIdx.x;
    if (t < n) deg[t] = rsqrtf(fmaxf(deg[t], 1.0f));
}

__global__ void hist_int_kernel(const int* __restrict__ idx, int* __restrict__ cnt, int E) {
    int t = blockIdx.x * blockDim.x + threadIdx.x;
    if (t < E) atomicAdd(&cnt[idx[t]], 1);
}

// ---------------- exclusive scan (3-phase) over NN ints ----------------
__global__ __launch_bounds__(256) void scan_phase_a(const int* __restrict__ in, int* __restrict__ part, int n) {
    __shared__ int sh[256];
    int tid = threadIdx.x;
    int base = blockIdx.x * 1024 + tid * 4;
    int s = 0;
#pragma unroll
    for (int i = 0; i < 4; i++) { int idx = base + i; if (idx < n) s += in[idx]; }
    sh[tid] = s; __syncthreads();
    for (int off = 128; off > 0; off >>= 1) {
        if (tid < off) sh[tid] += sh[tid + off];
        __syncthreads();
    }
    if (tid == 0) part[blockIdx.x] = sh[0];
}

__global__ void scan_phase_b(int* __restrict__ part, int nb) {
    __shared__ int sh[128];
    int tid = threadIdx.x;
    int v = (tid < nb) ? part[tid] : 0;
    sh[tid] = v; __syncthreads();
    for (int off = 1; off < 128; off <<= 1) {
        int t = (tid >= off) ? sh[tid - off] : 0;
        __syncthreads();
        sh[tid] += t;
        __syncthreads();
    }
    if (tid < nb) part[tid] = sh[tid] - v;   // exclusive
}

__global__ __launch_bounds__(256) void scan_phase_c(const int* __restrict__ in, const int* __restrict__ part,
                                                    int* __restrict__ row_ptr, float* __restrict__ rs,
                                                    int n, int E) {
    __shared__ int sh[256];
    int tid = threadIdx.x;
    int base = blockIdx.x * 1024 + tid * 4;
    int v[4]; int s = 0;
#pragma unroll
    for (int i = 0; i < 4; i++) { int idx = base + i; v[i] = (idx < n) ? in[idx] : 0; s += v[i]; }
    sh[tid] = s; __syncthreads();
    for (int off = 1; off < 256; off <<= 1) {
        int t = (tid >= off) ? sh[tid - off] : 0;
        __syncthreads();
        sh[tid] += t;
        __syncthreads();
    }
    int excl = sh[tid] - s + part[blockIdx.x];
#pragma unroll
    for (int i = 0; i < 4; i++) {
        int idx = base + i;
        if (idx < n) {
            row_ptr[idx] = excl;
            rs[idx] = rsqrtf(fmaxf((float)v[i], 1.0f));
            excl += v[i];
        }
    }
    if (blockIdx.x == 0 && tid == 0) row_ptr[n] = E;
}

// ---------------- CSR fill (counting sort by dst) ----------------
__global__ void fill_csr_kernel(const int* __restrict__ src, const int* __restrict__ dst,
                                const float* __restrict__ rs_src, int* __restrict__ cursor,
                                int* __restrict__ col, float* __restrict__ scl, int E) {
    int e = blockIdx.x * blockDim.x + threadIdx.x;
    if (e >= E) return;
    int s = src[e], d = dst[e];
    int p = atomicAdd(&cursor[d], 1);
    col[p] = s;
    scl[p] = rs_src[s];
}

// ---------------- gather aggregation: agg[d] = rs_dst[d] * sum_e scl[e]*x[col[e]] ----------------
__global__ __launch_bounds__(256) void gather_agg_kernel(const float* __restrict__ x,
                                                         const int* __restrict__ row_ptr,
                                                         const int* __restrict__ col,
                                                         const float* __restrict__ scl,
                                                         const float* __restrict__ rs_dst,
                                                         float* __restrict__ agg, int n) {
    int t = blockIdx.x * blockDim.x + threadIdx.x;
    int d = t >> 5;
    if (d >= n) return;
    int lane = t & 31;
    int j0 = row_ptr[d], j1 = row_ptr[d + 1];
    float4 acc = make_float4(0.f, 0.f, 0.f, 0.f);
    for (int j = j0; j < j1; j++) {
        int s = col[j];
        float sc = scl[j];
        float4 v = *reinterpret_cast<const float4*>(x + (size_t)s * 128 + lane * 4);
        acc.x += v.x * sc; acc.y += v.y * sc; acc.z += v.z * sc; acc.w += v.w * sc;
    }
    float rd = rs_dst[d];
    float4 o = make_float4(acc.x * rd, acc.y * rd, acc.z * rd, acc.w * rd);
    *reinterpret_cast<float4*>(agg + (size_t)d * 128 + lane * 4) = o;
}

// ---------------- fp32 tiled GEMM, K=128 fixed ----------------
#define BM 64
#define BN 128
#define BK 16

template <bool TRANS_B, bool RELU_A, bool HAS_ADDEND>
__global__ __launch_bounds__(256) void gemm128_kernel(
    const float* __restrict__ A, const float* __restrict__ B,
    const float* __restrict__ bias,
    const float* __restrict__ addend, float* __restrict__ C, int M, int N) {
    __shared__ float As[BM][BK + 4];
    __shared__ float Bs[BK][BN + 4];

    const int tid = threadIdx.x;
    const int row0 = blockIdx.y * BM;
    const int col0 = blockIdx.x * BN;
    const int tx = tid & 15;
    const int ty = tid >> 4;

    float acc[4][8];
#pragma unroll
    for (int i = 0; i < 4; i++)
#pragma unroll
        for (int j = 0; j < 8; j++) acc[i][j] = 0.0f;

    for (int k0 = 0; k0 < 128; k0 += BK) {
        {
            int r = tid >> 2;
            int c4 = (tid & 3) * 4;
            int grow = row0 + r;
            float4 v = make_float4(0.f, 0.f, 0.f, 0.f);
            if (grow < M) {
                v = *reinterpret_cast<const float4*>(A + (size_t)grow * 128 + k0 + c4);
                if (RELU_A) {
                    v.x = fmaxf(v.x, 0.f); v.y = fmaxf(v.y, 0.f);
                    v.z = fmaxf(v.z, 0.f); v.w = fmaxf(v.w, 0.f);
                }
            }
            *reinterpret_cast<float4*>(&As[r][c4]) = v;
        }
        if (!TRANS_B) {
#pragma unroll
            for (int l = 0; l < 2; l++) {
                int idx = tid + l * 256;
                int r = idx >> 5;
                int c4 = (idx & 31) * 4;
                float4 v = *reinterpret_cast<const float4*>(B + (size_t)(k0 + r) * N + col0 + c4);
                *reinterpret_cast<float4*>(&Bs[r][c4]) = v;
            }
        } else {
#pragma unroll
            for (int l = 0; l < 2; l++) {
                int idx = tid + l * 256;
                int c = idx >> 2;
                int r4 = (idx & 3) * 4;
                float4 v = *reinterpret_cast<const float4*>(B + (size_t)(col0 + c) * 128 + k0 + r4);
                Bs[r4 + 0][c] = v.x;
                Bs[r4 + 1][c] = v.y;
                Bs[r4 + 2][c] = v.z;
                Bs[r4 + 3][c] = v.w;
            }
        }
        __syncthreads();

#pragma unroll
        for (int kk = 0; kk < BK; kk++) {
            float a[4], b[8];
#pragma unroll
            for (int i = 0; i < 4; i++) a[i] = As[ty + 16 * i][kk];
#pragma unroll
            for (int j = 0; j < 8; j++) b[j] = Bs[kk][tx + 16 * j];
#pragma unroll
            for (int i = 0; i < 4; i++)
#pragma unroll
                for (int j = 0; j < 8; j++) acc[i][j] += a[i] * b[j];
        }
        __syncthreads();
    }

#pragma unroll
    for (int i = 0; i < 4; i++) {
        int grow = row0 + ty + 16 * i;
        if (grow >= M) continue;
#pragma unroll
        for (int j = 0; j < 8; j++) {
            int gcol = col0 + tx + 16 * j;
            float v = acc[i][j] + bias[gcol];
            if (HAS_ADDEND) v += addend[(size_t)grow * N + gcol];
            C[(size_t)grow * N + gcol] = v;
        }
    }
}

// ---------------- GRU gates ----------------
__global__ void gru_gates_kernel(const float* __restrict__ gi, const float* __restrict__ gh,
                                 const float* __restrict__ h, float* __restrict__ out, int rows) {
    int idx = blockIdx.x * blockDim.x + threadIdx.x;
    if (idx >= rows * 128) return;
    int r = idx >> 7, c = idx & 127;
    const float* gir = gi + (size_t)r * 384;
    const float* ghr = gh + (size_t)r * 384;
    float ir = gir[c], iz = gir[128 + c], in = gir[256 + c];
    float hr = ghr[c], hz = ghr[128 + c], hn = ghr[256 + c];
    float rr = 1.0f / (1.0f + expf(-(ir + hr)));
    float z  = 1.0f / (1.0f + expf(-(iz + hz)));
    float n  = tanhf(in + rr * hn);
    float hv = h[idx];
    out[idx] = (1.0f - z) * n + z * hv;
}

// ---------------- launch ----------------
extern "C" void kernel_launch(void* const* d_in, const int* in_sizes, int n_in,
                              void* d_out, int out_size, void* d_ws, size_t ws_size,
                              hipStream_t stream) {
    const float* feat_user = (const float*)d_in[0];
    const float* feat_item = (const float*)d_in[1];
    const float* hidden0   = (const float*)d_in[2];

    const int* srcs[4] = {(const int*)d_in[3], (const int*)d_in[9], (const int*)d_in[15], (const int*)d_in[21]};
    const int* dsts[4] = {(const int*)d_in[4], (const int*)d_in[10], (const int*)d_in[16], (const int*)d_in[22]};
    // relation order: 0=follows(U->U) 1=buys(U->I) 2=revbuys(I->U) 3=similar(I->I)
    const float* W1[4] = {(const float*)d_in[5],  (const float*)d_in[11], (const float*)d_in[17], (const float*)d_in[23]};
    const float* b1[4] = {(const float*)d_in[6],  (const float*)d_in[12], (const float*)d_in[18], (const float*)d_in[24]};
    const float* W2[4] = {(const float*)d_in[7],  (const float*)d_in[13], (const float*)d_in[19], (const float*)d_in[25]};
    const float* b2[4] = {(const float*)d_in[8],  (const float*)d_in[14], (const float*)d_in[20], (const float*)d_in[26]};

    const float* wih = (const float*)d_in[27];
    const float* whh = (const float*)d_in[28];
    const float* bih = (const float*)d_in[29];
    const float* bhh = (const float*)d_in[30];

    // ---- workspace layout ----
    char* w = (char*)d_ws;
    auto alloc = [&](size_t bytes) { char* r = w; w += (bytes + 255) & ~(size_t)255; return r; };
    float* rs_src[4]; float* rs_dst[4]; int* row_ptr[4]; int* col[4]; float* scl[4];
    for (int r = 0; r < 4; r++) rs_src[r] = (float*)alloc(NN * sizeof(float));
    for (int r = 0; r < 4; r++) rs_dst[r] = (float*)alloc(NN * sizeof(float));
    for (int r = 0; r < 4; r++) row_ptr[r] = (int*)alloc((NN + 1) * sizeof(int));
    for (int r = 0; r < 4; r++) col[r] = (int*)alloc(NE * sizeof(int));
    for (int r = 0; r < 4; r++) scl[r] = (float*)alloc(NE * sizeof(float));
    int* cursor = (int*)alloc(NN * sizeof(int));
    int* part   = (int*)alloc(128 * sizeof(int));
    float* aggA = (float*)alloc((size_t)NN * 128 * sizeof(float));
    float* aggB = (float*)alloc((size_t)NN * 128 * sizeof(float));

    float* outLo = (float*)d_out;
    float* outHi = outLo + (size_t)NU * 128;

    const int EB = (NE + 255) / 256;
    const int NBn = (NN + 255) / 256;

    // ---- build CSR + degree scales for all 4 relations ----
    for (int r = 0; r < 4; r++) {
        hipMemsetAsync(cursor, 0, NN * sizeof(int), stream);
        hist_int_kernel<<<EB, 256, 0, stream>>>(dsts[r], cursor, NE);
        scan_phase_a<<<NB_SCAN, 256, 0, stream>>>(cursor, part, NN);
        scan_phase_b<<<1, 128, 0, stream>>>(part, NB_SCAN);
        scan_phase_c<<<NB_SCAN, 256, 0, stream>>>(cursor, part, row_ptr[r], rs_dst[r], NN, NE);
        hipMemsetAsync(rs_src[r], 0, NN * sizeof(float), stream);
        deg_count_kernel<<<EB, 256, 0, stream>>>(srcs[r], rs_src[r], NE);
        rsqrt_clip_kernel<<<NBn, 256, 0, stream>>>(rs_src[r], NN);
        hipMemcpyAsync(cursor, row_ptr[r], NN * sizeof(int), hipMemcpyDeviceToDevice, stream);
        fill_csr_kernel<<<EB, 256, 0, stream>>>(srcs[r], dsts[r], rs_src[r], cursor, col[r], scl[r], NE);
    }

    auto gather = [&](int r, const float* x, float* agg) {
        gather_agg_kernel<<<(NN * 32 + 255) / 256, 256, 0, stream>>>(
            x, row_ptr[r], col[r], scl[r], rs_dst[r], agg, NN);
    };
    auto gemm_conv = [&](const float* A, const float* Wm, const float* b, const float* add, float* C) {
        dim3 g(1, (NN + BM - 1) / BM);
        if (add)
            gemm128_kernel<false, false, true><<<g, 256, 0, stream>>>(A, Wm, b, add, C, NN, 128);
        else
            gemm128_kernel<false, false, false><<<g, 256, 0, stream>>>(A, Wm, b, nullptr, C, NN, 128);
    };

    // ---- layer 1 (pre-activation hu/hi into d_out; relu deferred to GRU A-load) ----
    gather(0, feat_user, aggA);                 // follows
    gather(2, feat_item, aggB);                 // revbuys
    gemm_conv(aggA, W1[0], b1[0], nullptr, aggA);        // in-place
    gemm_conv(aggB, W1[2], b1[2], aggA, outLo);          // hu_pre
    gather(1, feat_user, aggA);                 // buys
    gather(3, feat_item, aggB);                 // similar
    gemm_conv(aggA, W1[1], b1[1], nullptr, aggA);        // in-place
    gemm_conv(aggB, W1[3], b1[3], aggA, outHi);          // hi_pre

    // ---- GRU (chunked; gi->aggA, gh->aggB; writes hc in place over d_out) ----
    const int RCH = 32768;
    for (int r0 = 0; r0 < NTOT; r0 += RCH) {
        int m = NTOT - r0; if (m > RCH) m = RCH;
        dim3 g(3, (m + BM - 1) / BM);
        gemm128_kernel<true, true, false><<<g, 256, 0, stream>>>(
            outLo + (size_t)r0 * 128, wih, bih, nullptr, aggA, m, 384);
        gemm128_kernel<true, false, false><<<g, 256, 0, stream>>>(
            hidden0 + (size_t)r0 * 128, whh, bhh, nullptr, aggB, m, 384);
        gru_gates_kernel<<<(m * 128 + 255) / 256, 256, 0, stream>>>(
            aggA, aggB, hidden0 + (size_t)r0 * 128, outLo + (size_t)r0 * 128, m);
    }

    // ---- layer 2 (hu = outLo, hi = outHi) ----
    gather(0, outLo, aggA);                     // follows(hu)
    gemm_conv(aggA, W2[0], b2[0], nullptr, aggA);        // in-place: follows part of ou
    gather(1, outLo, aggB);                     // buys(hu); hu dead after this
    gemm_conv(aggB, W2[1], b2[1], nullptr, aggB);        // in-place: buys part of oi
    gather(2, outHi, outLo);                    // revbuys(hi) -> writes over hu
    gemm_conv(outLo, W2[2], b2[2], aggA, outLo);         // ou = revbuys + follows (in-place)
    gather(3, outHi, aggA);                     // similar(hi)
    gemm_conv(aggA, W2[3], b2[3], aggB, outHi);          // oi = similar + buys
}

// Round 3
// 1187.595 us; speedup vs baseline: 3.6115x; 1.5216x over previous
//
#include <hip/hip_runtime.h>
#include <math.h>

#define NU 100000
#define NI 100000
#define NE 200000
#define NTOT (NU + NI)
#define NN 100000
#define NB_SCAN ((NN + 1023) / 1024)   // 98

typedef __bf16 bf16x8 __attribute__((ext_vector_type(8)));
typedef float f32x4 __attribute__((ext_vector_type(4)));
#define MFMA(a, b, c) __builtin_amdgcn_mfma_f32_16x16x32_bf16(a, b, c, 0, 0, 0)

__device__ __forceinline__ ushort f2bf(float f) {
    uint u = __float_as_uint(f);
    return (ushort)((u + 0x7FFFu + ((u >> 16) & 1u)) >> 16);
}
__device__ __forceinline__ float bf2f(ushort h) {
    return __uint_as_float(((uint)h) << 16);
}

// ---------------- degree / histogram kernels ----------------
__global__ void deg_count_kernel(const int* __restrict__ idx, float* __restrict__ deg, int E) {
    int t = blockIdx.x * blockDim.x + threadIdx.x;
    if (t < E) atomicAdd(&deg[idx[t]], 1.0f);
}

__global__ void rsqrt_clip_kernel(float* __restrict__ deg, int n) {
    int t = blockIdx.x * blockDim.x + threadIdx.x;
    if (t < n) deg[t] = rsqrtf(fmaxf(deg[t], 1.0f));
}

__global__ void hist_int_kernel(const int* __restrict__ idx, int* __restrict__ cnt, int E) {
    int t = blockIdx.x * blockDim.x + threadIdx.x;
    if (t < E) atomicAdd(&cnt[idx[t]], 1);
}

// ---------------- exclusive scan (3-phase) over NN ints ----------------
__global__ __launch_bounds__(256) void scan_phase_a(const int* __restrict__ in, int* __restrict__ part, int n) {
    __shared__ int sh[256];
    int tid = threadIdx.x;
    int base = blockIdx.x * 1024 + tid * 4;
    int s = 0;
#pragma unroll
    for (int i = 0; i < 4; i++) { int idx = base + i; if (idx < n) s += in[idx]; }
    sh[tid] = s; __syncthreads();
    for (int off = 128; off > 0; off >>= 1) {
        if (tid < off) sh[tid] += sh[tid + off];
        __syncthreads();
    }
    if (tid == 0) part[blockIdx.x] = sh[0];
}

__global__ void scan_phase_b(int* __restrict__ part, int nb) {
    __shared__ int sh[128];
    int tid = threadIdx.x;
    int v = (tid < nb) ? part[tid] : 0;
    sh[tid] = v; __syncthreads();
    for (int off = 1; off < 128; off <<= 1) {
        int t = (tid >= off) ? sh[tid - off] : 0;
        __syncthreads();
        sh[tid] += t;
        __syncthreads();
    }
    if (tid < nb) part[tid] = sh[tid] - v;   // exclusive
}

__global__ __launch_bounds__(256) void scan_phase_c(const int* __restrict__ in, const int* __restrict__ part,
                                                    int* __restrict__ row_ptr, float* __restrict__ rs,
                                                    int n, int E) {
    __shared__ int sh[256];
    int tid = threadIdx.x;
    int base = blockIdx.x * 1024 + tid * 4;
    int v[4]; int s = 0;
#pragma unroll
    for (int i = 0; i < 4; i++) { int idx = base + i; v[i] = (idx < n) ? in[idx] : 0; s += v[i]; }
    sh[tid] = s; __syncthreads();
    for (int off = 1; off < 256; off <<= 1) {
        int t = (tid >= off) ? sh[tid - off] : 0;
        __syncthreads();
        sh[tid] += t;
        __syncthreads();
    }
    int excl = sh[tid] - s + part[blockIdx.x];
#pragma unroll
    for (int i = 0; i < 4; i++) {
        int idx = base + i;
        if (idx < n) {
            row_ptr[idx] = excl;
            rs[idx] = rsqrtf(fmaxf((float)v[i], 1.0f));
            excl += v[i];
        }
    }
    if (blockIdx.x == 0 && tid == 0) row_ptr[n] = E;
}

// ---------------- CSR fill (counting sort by dst) ----------------
__global__ void fill_csr_kernel(const int* __restrict__ src, const int* __restrict__ dst,
                                const float* __restrict__ rs_src, int* __restrict__ cursor,
                                int* __restrict__ col, float* __restrict__ scl, int E) {
    int e = blockIdx.x * blockDim.x + threadIdx.x;
    if (e >= E) return;
    int s = src[e], d = dst[e];
    int p = atomicAdd(&cursor[d], 1);
    col[p] = s;
    scl[p] = rs_src[s];
}

// ---------------- gather aggregation ----------------
__global__ __launch_bounds__(256) void gather_agg_kernel(const float* __restrict__ x,
                                                         const int* __restrict__ row_ptr,
                                                         const int* __restrict__ col,
                                                         const float* __restrict__ scl,
                                                         const float* __restrict__ rs_dst,
                                                         float* __restrict__ agg, int n) {
    int t = blockIdx.x * blockDim.x + threadIdx.x;
    int d = t >> 5;
    if (d >= n) return;
    int lane = t & 31;
    int j0 = row_ptr[d], j1 = row_ptr[d + 1];
    float4 acc = make_float4(0.f, 0.f, 0.f, 0.f);
    for (int j = j0; j < j1; j++) {
        int s = col[j];
        float sc = scl[j];
        float4 v = *reinterpret_cast<const float4*>(x + (size_t)s * 128 + lane * 4);
        acc.x += v.x * sc; acc.y += v.y * sc; acc.z += v.z * sc; acc.w += v.w * sc;
    }
    float rd = rs_dst[d];
    float4 o = make_float4(acc.x * rd, acc.y * rd, acc.z * rd, acc.w * rd);
    *reinterpret_cast<float4*>(agg + (size_t)d * 128 + lane * 4) = o;
}

// ---------------- weight pack: B[k][n] -> MFMA B-fragment order, split bf16 ----------------
// layout: pack[((nf*4 + ks)*64 + l)*8 + j] = B[ks*32 + (l>>4)*8 + j][nf*16 + (l&15)]
__global__ void pack_w_kernel(const float* __restrict__ W, ushort* __restrict__ hi,
                              ushort* __restrict__ lo, int N, int K, int trans, int total) {
    int tid = blockIdx.x * blockDim.x + threadIdx.x;
    if (tid >= total) return;
    int j = tid & 7;
    int l = (tid >> 3) & 63;
    int ks = (tid >> 9) & 3;
    int nf = tid >> 11;
    int k = ks * 32 + ((l >> 4) << 3) + j;
    int n = nf * 16 + (l & 15);
    float v = trans ? W[(size_t)n * K + k] : W[(size_t)k * N + n];
    ushort h = f2bf(v);
    hi[tid] = h;
    lo[tid] = f2bf(v - bf2f(h));
}

// ---------------- MFMA GEMM: C(Mx128) = A(Mx128) @ B(128x128) + bias (+addend) ----------------
// split-bf16: 3 MFMAs per fragment. Block = 256 thr (4 waves), 128 rows x 128 cols.
// In-place safe (C==A): block stages all its A rows into LDS before any C write.
template <bool RELU_A, bool HAS_ADDEND>
__global__ __launch_bounds__(256) void gemm_mfma_kernel(
    const float* __restrict__ A, const ushort* __restrict__ wh, const ushort* __restrict__ wl,
    const float* __restrict__ bias, const float* __restrict__ addend,
    float* __restrict__ C, int M) {
    __shared__ __align__(16) ushort Ah[128 * 128];
    __shared__ __align__(16) ushort Al[128 * 128];
    const int tid = threadIdx.x;
    const int row0 = blockIdx.x * 128;

    // ---- stage A: fp32 -> split bf16, XOR-swizzled ----
#pragma unroll
    for (int it = 0; it < 16; ++it) {
        int i = it * 256 + tid;        // 0..4095 float4 slots (128 rows x 32)
        int r = i >> 5;
        int c4 = (i & 31) << 2;
        int gr = row0 + r;
        float4 v = make_float4(0.f, 0.f, 0.f, 0.f);
        if (gr < M) v = *reinterpret_cast<const float4*>(A + (size_t)gr * 128 + c4);
        if (RELU_A) {
            v.x = fmaxf(v.x, 0.f); v.y = fmaxf(v.y, 0.f);
            v.z = fmaxf(v.z, 0.f); v.w = fmaxf(v.w, 0.f);
        }
        ushort4 hi, lo;
        hi.x = f2bf(v.x); lo.x = f2bf(v.x - bf2f(hi.x));
        hi.y = f2bf(v.y); lo.y = f2bf(v.y - bf2f(hi.y));
        hi.z = f2bf(v.z); lo.z = f2bf(v.z - bf2f(hi.z));
        hi.w = f2bf(v.w); lo.w = f2bf(v.w - bf2f(hi.w));
        int base = (r * 128 + c4) ^ ((r & 7) << 3);
        *reinterpret_cast<ushort4*>(&Ah[base]) = hi;
        *reinterpret_cast<ushort4*>(&Al[base]) = lo;
    }
    __syncthreads();

    const int wv = tid >> 6;
    const int l = tid & 63;
    const int l15 = l & 15, lh = l >> 4;

    f32x4 acc[2][8];
#pragma unroll
    for (int m = 0; m < 2; m++)
#pragma unroll
        for (int nf = 0; nf < 8; nf++) acc[m][nf] = (f32x4)(0.f);

#pragma unroll
    for (int ks = 0; ks < 4; ++ks) {
        bf16x8 aH[2], aL[2];
#pragma unroll
        for (int m = 0; m < 2; ++m) {
            int row = wv * 32 + m * 16 + l15;
            int idx = (row * 128 + ks * 32 + lh * 8) ^ ((row & 7) << 3);
            aH[m] = *reinterpret_cast<const bf16x8*>(&Ah[idx]);
            aL[m] = *reinterpret_cast<const bf16x8*>(&Al[idx]);
        }
#pragma unroll
        for (int nf = 0; nf < 8; ++nf) {
            size_t off = ((size_t)(nf * 4 + ks) * 64 + l) * 8;
            bf16x8 bH = *reinterpret_cast<const bf16x8*>(wh + off);
            bf16x8 bL = *reinterpret_cast<const bf16x8*>(wl + off);
#pragma unroll
            for (int m = 0; m < 2; ++m) {
                acc[m][nf] = MFMA(aH[m], bH, acc[m][nf]);
                acc[m][nf] = MFMA(aL[m], bH, acc[m][nf]);
                acc[m][nf] = MFMA(aH[m], bL, acc[m][nf]);
            }
        }
    }

    // ---- epilogue: C[row][col], row = (lane>>4)*4 + i, col = lane&15 (m89 layout) ----
#pragma unroll
    for (int m = 0; m < 2; ++m) {
        int rbase = row0 + wv * 32 + m * 16 + lh * 4;
#pragma unroll
        for (int nf = 0; nf < 8; ++nf) {
            int c = nf * 16 + l15;
            float bv = bias[c];
#pragma unroll
            for (int i = 0; i < 4; ++i) {
                int gr = rbase + i;
                if (gr >= M) continue;
                float v = acc[m][nf][i] + bv;
                if (HAS_ADDEND) v += addend[(size_t)gr * 128 + c];
                C[(size_t)gr * 128 + c] = v;
            }
        }
    }
}

// ---------------- fused GRU (h0 == 0): x = relu(X), gi = x@wih^T+bih, gh = bhh ----------------
// r=sig(ir+bhh_r), z=sig(iz+bhh_z), n=tanh(in+r*bhh_n), out=(1-z)*n.  In-place over X.
__global__ __launch_bounds__(256) void gru_fused_kernel(
    float* __restrict__ X, const ushort* __restrict__ wh, const ushort* __restrict__ wl,
    const float* __restrict__ bih, const float* __restrict__ bhh, int M) {
    __shared__ __align__(16) ushort Ah[64 * 128];
    __shared__ __align__(16) ushort Al[64 * 128];
    const int tid = threadIdx.x;
    const int row0 = blockIdx.x * 64;

#pragma unroll
    for (int it = 0; it < 8; ++it) {
        int i = it * 256 + tid;        // 64 rows x 32 float4
        int r = i >> 5;
        int c4 = (i & 31) << 2;
        int gr = row0 + r;
        float4 v = make_float4(0.f, 0.f, 0.f, 0.f);
        if (gr < M) v = *reinterpret_cast<const float4*>(X + (size_t)gr * 128 + c4);
        v.x = fmaxf(v.x, 0.f); v.y = fmaxf(v.y, 0.f);
        v.z = fmaxf(v.z, 0.f); v.w = fmaxf(v.w, 0.f);
        ushort4 hi, lo;
        hi.x = f2bf(v.x); lo.x = f2bf(v.x - bf2f(hi.x));
        hi.y = f2bf(v.y); lo.y = f2bf(v.y - bf2f(hi.y));
        hi.z = f2bf(v.z); lo.z = f2bf(v.z - bf2f(hi.z));
        hi.w = f2bf(v.w); lo.w = f2bf(v.w - bf2f(hi.w));
        int base = (r * 128 + c4) ^ ((r & 7) << 3);
        *reinterpret_cast<ushort4*>(&Ah[base]) = hi;
        *reinterpret_cast<ushort4*>(&Al[base]) = lo;
    }
    __syncthreads();

    const int wv = tid >> 6;
    const int l = tid & 63;
    const int l15 = l & 15, lh = l >> 4;
    const int arow = wv * 16 + l15;

    f32x4 rv[8], zv[8];

#pragma unroll
    for (int g = 0; g < 3; ++g) {
        f32x4 acc[8];
#pragma unroll
        for (int nf = 0; nf < 8; nf++) acc[nf] = (f32x4)(0.f);
#pragma unroll
        for (int ks = 0; ks < 4; ++ks) {
            int idx = (arow * 128 + ks * 32 + lh * 8) ^ ((arow & 7) << 3);
            bf16x8 aH = *reinterpret_cast<const bf16x8*>(&Ah[idx]);
            bf16x8 aL = *reinterpret_cast<const bf16x8*>(&Al[idx]);
#pragma unroll
            for (int nf = 0; nf < 8; ++nf) {
                size_t off = ((size_t)((g * 8 + nf) * 4 + ks) * 64 + l) * 8;
                bf16x8 bH = *reinterpret_cast<const bf16x8*>(wh + off);
                bf16x8 bL = *reinterpret_cast<const bf16x8*>(wl + off);
                acc[nf] = MFMA(aH, bH, acc[nf]);
                acc[nf] = MFMA(aL, bH, acc[nf]);
                acc[nf] = MFMA(aH, bL, acc[nf]);
            }
        }
        if (g == 0) {
#pragma unroll
            for (int nf = 0; nf < 8; ++nf) {
                int c = nf * 16 + l15;
                float b = bih[c] + bhh[c];
#pragma unroll
                for (int i = 0; i < 4; ++i)
                    rv[nf][i] = 1.f / (1.f + expf(-(acc[nf][i] + b)));
            }
        } else if (g == 1) {
#pragma unroll
            for (int nf = 0; nf < 8; ++nf) {
                int c = nf * 16 + l15;
                float b = bih[128 + c] + bhh[128 + c];
#pragma unroll
                for (int i = 0; i < 4; ++i)
                    zv[nf][i] = 1.f / (1.f + expf(-(acc[nf][i] + b)));
            }
        } else {
#pragma unroll
            for (int nf = 0; nf < 8; ++nf) {
                int c = nf * 16 + l15;
                float bi = bih[256 + c], bh = bhh[256 + c];
                int rbase = row0 + wv * 16 + lh * 4;
#pragma unroll
                for (int i = 0; i < 4; ++i) {
                    int gr = rbase + i;
                    if (gr >= M) continue;
                    float n = tanhf(acc[nf][i] + bi + rv[nf][i] * bh);
                    X[(size_t)gr * 128 + c] = (1.f - zv[nf][i]) * n;
                }
            }
        }
    }
}

// ---------------- launch ----------------
extern "C" void kernel_launch(void* const* d_in, const int* in_sizes, int n_in,
                              void* d_out, int out_size, void* d_ws, size_t ws_size,
                              hipStream_t stream) {
    const float* feat_user = (const float*)d_in[0];
    const float* feat_item = (const float*)d_in[1];

    const int* srcs[4] = {(const int*)d_in[3], (const int*)d_in[9], (const int*)d_in[15], (const int*)d_in[21]};
    const int* dsts[4] = {(const int*)d_in[4], (const int*)d_in[10], (const int*)d_in[16], (const int*)d_in[22]};
    // relation order: 0=follows(U->U) 1=buys(U->I) 2=revbuys(I->U) 3=similar(I->I)
    const float* W1[4] = {(const float*)d_in[5],  (const float*)d_in[11], (const float*)d_in[17], (const float*)d_in[23]};
    const float* b1[4] = {(const float*)d_in[6],  (const float*)d_in[12], (const float*)d_in[18], (const float*)d_in[24]};
    const float* W2[4] = {(const float*)d_in[7],  (const float*)d_in[13], (const float*)d_in[19], (const float*)d_in[25]};
    const float* b2[4] = {(const float*)d_in[8],  (const float*)d_in[14], (const float*)d_in[20], (const float*)d_in[26]};

    const float* wih = (const float*)d_in[27];
    const float* bih = (const float*)d_in[29];
    const float* bhh = (const float*)d_in[30];

    // ---- workspace layout ----
    char* w = (char*)d_ws;
    auto alloc = [&](size_t bytes) { char* r = w; w += (bytes + 255) & ~(size_t)255; return r; };
    float* rs_src[4]; float* rs_dst[4]; int* row_ptr[4]; int* col[4]; float* scl[4];
    for (int r = 0; r < 4; r++) rs_src[r] = (float*)alloc(NN * sizeof(float));
    for (int r = 0; r < 4; r++) rs_dst[r] = (float*)alloc(NN * sizeof(float));
    for (int r = 0; r < 4; r++) row_ptr[r] = (int*)alloc((NN + 1) * sizeof(int));
    for (int r = 0; r < 4; r++) col[r] = (int*)alloc(NE * sizeof(int));
    for (int r = 0; r < 4; r++) scl[r] = (float*)alloc(NE * sizeof(float));
    int* cursor = (int*)alloc(NN * sizeof(int));
    int* part   = (int*)alloc(128 * sizeof(int));
    float* aggA = (float*)alloc((size_t)NN * 128 * sizeof(float));
    float* aggB = (float*)alloc((size_t)NN * 128 * sizeof(float));
    // weight packs: 8 conv (128x128) + 1 gru wih (128x384)
    ushort* pkh[9]; ushort* pkl[9];
    for (int i = 0; i < 8; i++) {
        pkh[i] = (ushort*)alloc(128 * 128 * sizeof(ushort));
        pkl[i] = (ushort*)alloc(128 * 128 * sizeof(ushort));
    }
    pkh[8] = (ushort*)alloc(128 * 384 * sizeof(ushort));
    pkl[8] = (ushort*)alloc(128 * 384 * sizeof(ushort));

    float* outLo = (float*)d_out;
    float* outHi = outLo + (size_t)NU * 128;

    const int EB = (NE + 255) / 256;
    const int NBn = (NN + 255) / 256;

    // ---- pack weights ----
    const float* convW[8] = {W1[0], W1[1], W1[2], W1[3], W2[0], W2[1], W2[2], W2[3]};
    for (int i = 0; i < 8; i++)
        pack_w_kernel<<<(128 * 128 + 255) / 256, 256, 0, stream>>>(convW[i], pkh[i], pkl[i], 128, 128, 0, 128 * 128);
    pack_w_kernel<<<(128 * 384 + 255) / 256, 256, 0, stream>>>(wih, pkh[8], pkl[8], 384, 128, 1, 128 * 384);

    // ---- build CSR + degree scales ----
    for (int r = 0; r < 4; r++) {
        hipMemsetAsync(cursor, 0, NN * sizeof(int), stream);
        hist_int_kernel<<<EB, 256, 0, stream>>>(dsts[r], cursor, NE);
        scan_phase_a<<<NB_SCAN, 256, 0, stream>>>(cursor, part, NN);
        scan_phase_b<<<1, 128, 0, stream>>>(part, NB_SCAN);
        scan_phase_c<<<NB_SCAN, 256, 0, stream>>>(cursor, part, row_ptr[r], rs_dst[r], NN, NE);
        hipMemsetAsync(rs_src[r], 0, NN * sizeof(float), stream);
        deg_count_kernel<<<EB, 256, 0, stream>>>(srcs[r], rs_src[r], NE);
        rsqrt_clip_kernel<<<NBn, 256, 0, stream>>>(rs_src[r], NN);
        hipMemcpyAsync(cursor, row_ptr[r], NN * sizeof(int), hipMemcpyDeviceToDevice, stream);
        fill_csr_kernel<<<EB, 256, 0, stream>>>(srcs[r], dsts[r], rs_src[r], cursor, col[r], scl[r], NE);
    }

    auto gather = [&](int r, const float* x, float* agg) {
        gather_agg_kernel<<<(NN * 32 + 255) / 256, 256, 0, stream>>>(
            x, row_ptr[r], col[r], scl[r], rs_dst[r], agg, NN);
    };
    const int GB = (NN + 127) / 128;
    auto gemm = [&](const float* A, int wi, const float* b, const float* add, float* C) {
        if (add)
            gemm_mfma_kernel<false, true><<<GB, 256, 0, stream>>>(A, pkh[wi], pkl[wi], b, add, C, NN);
        else
            gemm_mfma_kernel<false, false><<<GB, 256, 0, stream>>>(A, pkh[wi], pkl[wi], b, nullptr, C, NN);
    };

    // ---- layer 1 (pre-activation hu/hi into d_out; relu deferred to GRU load) ----
    gather(0, feat_user, aggA);                      // follows
    gather(2, feat_item, aggB);                      // revbuys
    gemm(aggA, 0, b1[0], nullptr, aggA);             // in-place
    gemm(aggB, 2, b1[2], aggA, outLo);               // hu_pre
    gather(1, feat_user, aggA);                      // buys
    gather(3, feat_item, aggB);                      // similar
    gemm(aggA, 1, b1[1], nullptr, aggA);             // in-place
    gemm(aggB, 3, b1[3], aggA, outHi);               // hi_pre

    // ---- fused GRU over all NTOT rows, in-place on d_out (h0 == 0) ----
    gru_fused_kernel<<<(NTOT + 63) / 64, 256, 0, stream>>>(outLo, pkh[8], pkl[8], bih, bhh, NTOT);

    // ---- layer 2 ----
    gather(0, outLo, aggA);                          // follows(hu)
    gemm(aggA, 4, b2[0], nullptr, aggA);             // in-place
    gather(1, outLo, aggB);                          // buys(hu); hu dead after this
    gemm(aggB, 5, b2[1], nullptr, aggB);             // in-place
    gather(2, outHi, outLo);                         // revbuys(hi) over hu
    gemm(outLo, 6, b2[2], aggA, outLo);              // ou = revbuys + follows (in-place)
    gather(3, outHi, aggA);                          // similar(hi)
    gemm(aggA, 7, b2[3], aggB, outHi);               // oi = similar + buys
}

// Round 4
// 741.748 us; speedup vs baseline: 5.7822x; 1.6011x over previous
//
#include <hip/hip_runtime.h>
#include <math.h>

#define NU 100000
#define NI 100000
#define NE 200000
#define NTOT (NU + NI)
#define NN 100000
#define NB_SCAN ((NN + 1023) / 1024)   // 98

typedef __bf16 bf16x8 __attribute__((ext_vector_type(8)));
typedef float f32x4 __attribute__((ext_vector_type(4)));
#define MFMA(a, b, c) __builtin_amdgcn_mfma_f32_16x16x32_bf16(a, b, c, 0, 0, 0)

__device__ __forceinline__ ushort f2bf(float f) {
    uint u = __float_as_uint(f);
    return (ushort)((u + 0x7FFFu + ((u >> 16) & 1u)) >> 16);
}
__device__ __forceinline__ float bf2f(ushort h) {
    return __uint_as_float(((uint)h) << 16);
}

struct Ptr4 { const int* p[4]; };
struct PackW { const float* w[9]; };

// ---------------- batched CSR build ----------------
__global__ void hist4_kernel(Ptr4 dst, int* __restrict__ cnt) {
    int e = blockIdx.x * blockDim.x + threadIdx.x;
    int r = blockIdx.y;
    if (e < NE) atomicAdd(&cnt[r * NN + dst.p[r][e]], 1);
}

__global__ void deg4_kernel(Ptr4 src, float* __restrict__ deg) {
    int e = blockIdx.x * blockDim.x + threadIdx.x;
    int r = blockIdx.y;
    if (e < NE) atomicAdd(&deg[r * NN + src.p[r][e]], 1.0f);
}

__global__ void rsqrt_clip_kernel(float* __restrict__ deg, int n) {
    int t = blockIdx.x * blockDim.x + threadIdx.x;
    if (t < n) deg[t] = rsqrtf(fmaxf(deg[t], 1.0f));
}

__global__ __launch_bounds__(256) void scan_phase_a(const int* __restrict__ in, int* __restrict__ part) {
    __shared__ int sh[256];
    int rel = blockIdx.y;
    const int* inp = in + rel * NN;
    int tid = threadIdx.x;
    int base = blockIdx.x * 1024 + tid * 4;
    int s = 0;
#pragma unroll
    for (int i = 0; i < 4; i++) { int idx = base + i; if (idx < NN) s += inp[idx]; }
    sh[tid] = s; __syncthreads();
    for (int off = 128; off > 0; off >>= 1) {
        if (tid < off) sh[tid] += sh[tid + off];
        __syncthreads();
    }
    if (tid == 0) part[rel * 128 + blockIdx.x] = sh[0];
}

__global__ void scan_phase_b(int* __restrict__ part) {
    __shared__ int sh[128];
    int rel = blockIdx.x;
    int tid = threadIdx.x;
    int v = (tid < NB_SCAN) ? part[rel * 128 + tid] : 0;
    sh[tid] = v; __syncthreads();
    for (int off = 1; off < 128; off <<= 1) {
        int t = (tid >= off) ? sh[tid - off] : 0;
        __syncthreads();
        sh[tid] += t;
        __syncthreads();
    }
    if (tid < NB_SCAN) part[rel * 128 + tid] = sh[tid] - v;   // exclusive
}

// reads counts from cnt, writes row_ptr, rs_dst, and overwrites cnt with start offsets (cursor)
__global__ __launch_bounds__(256) void scan_phase_c(int* __restrict__ cnt, const int* __restrict__ part,
                                                    int* __restrict__ row_ptr, float* __restrict__ rs) {
    __shared__ int sh[256];
    int rel = blockIdx.y;
    int* inp = cnt + rel * NN;
    int* rp = row_ptr + rel * (NN + 1);
    float* rsd = rs + rel * NN;
    int tid = threadIdx.x;
    int base = blockIdx.x * 1024 + tid * 4;
    int v[4]; int s = 0;
#pragma unroll
    for (int i = 0; i < 4; i++) { int idx = base + i; v[i] = (idx < NN) ? inp[idx] : 0; s += v[i]; }
    sh[tid] = s; __syncthreads();
    for (int off = 1; off < 256; off <<= 1) {
        int t = (tid >= off) ? sh[tid - off] : 0;
        __syncthreads();
        sh[tid] += t;
        __syncthreads();
    }
    int excl = sh[tid] - s + part[rel * 128 + blockIdx.x];
#pragma unroll
    for (int i = 0; i < 4; i++) {
        int idx = base + i;
        if (idx < NN) {
            rp[idx] = excl;
            inp[idx] = excl;                     // cursor init
            rsd[idx] = rsqrtf(fmaxf((float)v[i], 1.0f));
            excl += v[i];
        }
    }
    if (blockIdx.x == 0 && tid == 0) rp[NN] = NE;
}

__global__ void fill4_kernel(Ptr4 src, Ptr4 dst, const float* __restrict__ rs_src,
                             int* __restrict__ cursor, int* __restrict__ col, float* __restrict__ scl) {
    int e = blockIdx.x * blockDim.x + threadIdx.x;
    int r = blockIdx.y;
    if (e >= NE) return;
    int s = src.p[r][e], d = dst.p[r][e];
    int p = atomicAdd(&cursor[r * NN + d], 1);
    col[(size_t)r * NE + p] = s;
    scl[(size_t)r * NE + p] = rs_src[r * NN + s];
}

// ---------------- weight pack (all 9 weights, one dispatch) ----------------
// pack[((nf*4 + ks)*64 + l)*8 + j] = B[ks*32 + (l>>4)*8 + j][nf*16 + (l&15)]
__global__ void pack_all_kernel(PackW pw, ushort* __restrict__ hi, ushort* __restrict__ lo) {
    int tid = blockIdx.x * blockDim.x + threadIdx.x;
    int wi, local, N, trans;
    if (tid < 8 * 16384) { wi = tid >> 14; local = tid & 16383; N = 128; trans = 0; }
    else {
        int t = tid - 8 * 16384;
        if (t >= 49152) return;
        wi = 8; local = t; N = 384; trans = 1;
    }
    int j = local & 7;
    int l = (local >> 3) & 63;
    int ks = (local >> 9) & 3;
    int nf = local >> 11;
    int k = ks * 32 + ((l >> 4) << 3) + j;
    int n = nf * 16 + (l & 15);
    const float* W = pw.w[wi];
    float v = trans ? W[(size_t)n * 128 + k] : W[(size_t)k * N + n];
    size_t d = (size_t)wi * 16384 + local;
    ushort h = f2bf(v);
    hi[d] = h;
    lo[d] = f2bf(v - bf2f(h));
}

// ---------------- fused graph-conv: gather -> LDS(split bf16) -> MFMA -> C ----------------
// C[d] = (rs_dst[d] * sum_e scl[e]*x[col[e]]) @ W + bias (+ addend[d])
// 512 threads, 128 dst rows per block. addend may alias C (row-local read-before-write).
template <bool HAS_ADDEND>
__global__ __launch_bounds__(512) void fconv_kernel(
    const float* __restrict__ x, const int* __restrict__ row_ptr,
    const int* __restrict__ col, const float* __restrict__ scl,
    const float* __restrict__ rs_dst, const ushort* __restrict__ wh,
    const ushort* __restrict__ wl, const float* __restrict__ bias,
    const float* __restrict__ addend, float* __restrict__ C, int n) {
    __shared__ __align__(16) ushort Ah[128 * 128];
    __shared__ __align__(16) ushort Al[128 * 128];
    const int tid = threadIdx.x;
    const int row0 = blockIdx.x * 128;

    // ---- gather phase: 4 threads per row, 32 cols each ----
    {
        const int r = tid >> 2, q = tid & 3;
        const int d = row0 + r;
        f32x4 acc[8];
#pragma unroll
        for (int k = 0; k < 8; k++) acc[k] = (f32x4)(0.f);
        if (d < n) {
            int j0 = row_ptr[d], j1 = row_ptr[d + 1];
            for (int j = j0; j < j1; ++j) {
                int s = col[j];
                float sc = scl[j];
                const f32x4* xp = (const f32x4*)(x + (size_t)s * 128 + q * 32);
#pragma unroll
                for (int k = 0; k < 8; k++) acc[k] += xp[k] * sc;
            }
            float rd = rs_dst[d];
#pragma unroll
            for (int k = 0; k < 8; k++) acc[k] *= rd;
        }
#pragma unroll
        for (int k = 0; k < 8; k++) {
            ushort4 hi, lo;
            hi.x = f2bf(acc[k][0]); lo.x = f2bf(acc[k][0] - bf2f(hi.x));
            hi.y = f2bf(acc[k][1]); lo.y = f2bf(acc[k][1] - bf2f(hi.y));
            hi.z = f2bf(acc[k][2]); lo.z = f2bf(acc[k][2] - bf2f(hi.z));
            hi.w = f2bf(acc[k][3]); lo.w = f2bf(acc[k][3] - bf2f(hi.w));
            int base = (r * 128 + q * 32 + k * 4) ^ ((r & 7) << 3);
            *reinterpret_cast<ushort4*>(&Ah[base]) = hi;
            *reinterpret_cast<ushort4*>(&Al[base]) = lo;
        }
    }
    __syncthreads();

    // ---- MFMA phase: 8 waves = 2 row-halves x 4 nf-pairs ----
    const int wv = tid >> 6, l = tid & 63;
    const int l15 = l & 15, lh = l >> 4;
    const int rh = wv >> 2, np = wv & 3;

    f32x4 acc[4][2];
#pragma unroll
    for (int m = 0; m < 4; m++)
#pragma unroll
        for (int nfi = 0; nfi < 2; nfi++) acc[m][nfi] = (f32x4)(0.f);

#pragma unroll
    for (int ks = 0; ks < 4; ++ks) {
        bf16x8 aH[4], aL[4];
#pragma unroll
        for (int m = 0; m < 4; ++m) {
            int row = rh * 64 + m * 16 + l15;
            int idx = (row * 128 + ks * 32 + lh * 8) ^ ((row & 7) << 3);
            aH[m] = *reinterpret_cast<const bf16x8*>(&Ah[idx]);
            aL[m] = *reinterpret_cast<const bf16x8*>(&Al[idx]);
        }
#pragma unroll
        for (int nfi = 0; nfi < 2; ++nfi) {
            int nf = np * 2 + nfi;
            size_t off = ((size_t)(nf * 4 + ks) * 64 + l) * 8;
            bf16x8 bH = *reinterpret_cast<const bf16x8*>(wh + off);
            bf16x8 bL = *reinterpret_cast<const bf16x8*>(wl + off);
#pragma unroll
            for (int m = 0; m < 4; ++m) {
                acc[m][nfi] = MFMA(aH[m], bH, acc[m][nfi]);
                acc[m][nfi] = MFMA(aL[m], bH, acc[m][nfi]);
                acc[m][nfi] = MFMA(aH[m], bL, acc[m][nfi]);
            }
        }
    }

    // ---- epilogue ----
#pragma unroll
    for (int m = 0; m < 4; ++m) {
        int rbase = row0 + rh * 64 + m * 16 + lh * 4;
#pragma unroll
        for (int nfi = 0; nfi < 2; ++nfi) {
            int c = (np * 2 + nfi) * 16 + l15;
            float bv = bias[c];
#pragma unroll
            for (int i = 0; i < 4; ++i) {
                int gr = rbase + i;
                if (gr < n) {
                    float v = acc[m][nfi][i] + bv;
                    if (HAS_ADDEND) v += addend[(size_t)gr * 128 + c];
                    C[(size_t)gr * 128 + c] = v;
                }
            }
        }
    }
}

// ---------------- fused GRU (h0 == 0): out = (1-z)*tanh(in + r*bhh_n) ----------------
// 512 threads, 128 rows per block; wave owns nf-pair across all 3 gates.
__global__ __launch_bounds__(512) void gru_fused_kernel(
    const float* __restrict__ X, float* __restrict__ out,
    const ushort* __restrict__ wh, const ushort* __restrict__ wl,
    const float* __restrict__ bih, const float* __restrict__ bhh, int M) {
    __shared__ __align__(16) ushort Ah[128 * 128];
    __shared__ __align__(16) ushort Al[128 * 128];
    const int tid = threadIdx.x;
    const int row0 = blockIdx.x * 128;

    // ---- stage: relu(X) -> split bf16 -> LDS ----
    {
        const int r = tid >> 2, q = tid & 3;
        const int gr = row0 + r;
        const f32x4* xp = (const f32x4*)(X + (size_t)gr * 128 + q * 32);
#pragma unroll
        for (int k = 0; k < 8; ++k) {
            f32x4 v = (gr < M) ? xp[k] : (f32x4)(0.f);
            ushort4 hi, lo;
            float e;
            e = fmaxf(v[0], 0.f); hi.x = f2bf(e); lo.x = f2bf(e - bf2f(hi.x));
            e = fmaxf(v[1], 0.f); hi.y = f2bf(e); lo.y = f2bf(e - bf2f(hi.y));
            e = fmaxf(v[2], 0.f); hi.z = f2bf(e); lo.z = f2bf(e - bf2f(hi.z));
            e = fmaxf(v[3], 0.f); hi.w = f2bf(e); lo.w = f2bf(e - bf2f(hi.w));
            int base = (r * 128 + q * 32 + k * 4) ^ ((r & 7) << 3);
            *reinterpret_cast<ushort4*>(&Ah[base]) = hi;
            *reinterpret_cast<ushort4*>(&Al[base]) = lo;
        }
    }
    __syncthreads();

    const int wv = tid >> 6, l = tid & 63;
    const int l15 = l & 15, lh = l >> 4;
    const int rh = wv >> 2, np = wv & 3;

    f32x4 rv[4][2], zv[4][2];

#pragma unroll
    for (int g = 0; g < 3; ++g) {
        f32x4 acc[4][2];
#pragma unroll
        for (int m = 0; m < 4; m++)
#pragma unroll
            for (int nfi = 0; nfi < 2; nfi++) acc[m][nfi] = (f32x4)(0.f);

#pragma unroll
        for (int ks = 0; ks < 4; ++ks) {
            bf16x8 aH[4], aL[4];
#pragma unroll
            for (int m = 0; m < 4; ++m) {
                int row = rh * 64 + m * 16 + l15;
                int idx = (row * 128 + ks * 32 + lh * 8) ^ ((row & 7) << 3);
                aH[m] = *reinterpret_cast<const bf16x8*>(&Ah[idx]);
                aL[m] = *reinterpret_cast<const bf16x8*>(&Al[idx]);
            }
#pragma unroll
            for (int nfi = 0; nfi < 2; ++nfi) {
                int gnf = g * 8 + np * 2 + nfi;
                size_t off = ((size_t)(gnf * 4 + ks) * 64 + l) * 8;
                bf16x8 bH = *reinterpret_cast<const bf16x8*>(wh + off);
                bf16x8 bL = *reinterpret_cast<const bf16x8*>(wl + off);
#pragma unroll
                for (int m = 0; m < 4; ++m) {
                    acc[m][nfi] = MFMA(aH[m], bH, acc[m][nfi]);
                    acc[m][nfi] = MFMA(aL[m], bH, acc[m][nfi]);
                    acc[m][nfi] = MFMA(aH[m], bL, acc[m][nfi]);
                }
            }
        }

        if (g == 0) {
#pragma unroll
            for (int m = 0; m < 4; ++m)
#pragma unroll
                for (int nfi = 0; nfi < 2; ++nfi) {
                    int c = (np * 2 + nfi) * 16 + l15;
                    float b = bih[c] + bhh[c];
#pragma unroll
                    for (int i = 0; i < 4; ++i)
                        rv[m][nfi][i] = 1.f / (1.f + expf(-(acc[m][nfi][i] + b)));
                }
        } else if (g == 1) {
#pragma unroll
            for (int m = 0; m < 4; ++m)
#pragma unroll
                for (int nfi = 0; nfi < 2; ++nfi) {
                    int c = (np * 2 + nfi) * 16 + l15;
                    float b = bih[128 + c] + bhh[128 + c];
#pragma unroll
                    for (int i = 0; i < 4; ++i)
                        zv[m][nfi][i] = 1.f / (1.f + expf(-(acc[m][nfi][i] + b)));
                }
        } else {
#pragma unroll
            for (int m = 0; m < 4; ++m) {
                int rbase = row0 + rh * 64 + m * 16 + lh * 4;
#pragma unroll
                for (int nfi = 0; nfi < 2; ++nfi) {
                    int c = (np * 2 + nfi) * 16 + l15;
                    float bi = bih[256 + c], bh = bhh[256 + c];
#pragma unroll
                    for (int i = 0; i < 4; ++i) {
                        int gr = rbase + i;
                        if (gr < M) {
                            float nn = tanhf(acc[m][nfi][i] + bi + rv[m][nfi][i] * bh);
                            out[(size_t)gr * 128 + c] = (1.f - zv[m][nfi][i]) * nn;
                        }
                    }
                }
            }
        }
    }
}

// ---------------- launch ----------------
extern "C" void kernel_launch(void* const* d_in, const int* in_sizes, int n_in,
                              void* d_out, int out_size, void* d_ws, size_t ws_size,
                              hipStream_t stream) {
    const float* feat_user = (const float*)d_in[0];
    const float* feat_item = (const float*)d_in[1];

    // relation order: 0=follows(U->U) 1=buys(U->I) 2=revbuys(I->U) 3=similar(I->I)
    Ptr4 srcs = {{(const int*)d_in[3], (const int*)d_in[9], (const int*)d_in[15], (const int*)d_in[21]}};
    Ptr4 dsts = {{(const int*)d_in[4], (const int*)d_in[10], (const int*)d_in[16], (const int*)d_in[22]}};
    const float* b1[4] = {(const float*)d_in[6],  (const float*)d_in[12], (const float*)d_in[18], (const float*)d_in[24]};
    const float* b2[4] = {(const float*)d_in[8],  (const float*)d_in[14], (const float*)d_in[20], (const float*)d_in[26]};

    PackW pw = {{(const float*)d_in[5], (const float*)d_in[11], (const float*)d_in[17], (const float*)d_in[23],
                 (const float*)d_in[7], (const float*)d_in[13], (const float*)d_in[19], (const float*)d_in[25],
                 (const float*)d_in[27]}};
    const float* bih = (const float*)d_in[29];
    const float* bhh = (const float*)d_in[30];

    // ---- workspace layout ----
    char* w = (char*)d_ws;
    auto alloc = [&](size_t bytes) { char* r = w; w += (bytes + 255) & ~(size_t)255; return r; };
    float* rs_src_all = (float*)alloc(4 * NN * sizeof(float));
    float* rs_dst_all = (float*)alloc(4 * NN * sizeof(float));
    int* row_ptr_all  = (int*)alloc(4 * (NN + 1) * sizeof(int));
    int* cursor_all   = (int*)alloc(4 * NN * sizeof(int));
    int* col_all      = (int*)alloc((size_t)4 * NE * sizeof(int));
    float* scl_all    = (float*)alloc((size_t)4 * NE * sizeof(float));
    int* part         = (int*)alloc(4 * 128 * sizeof(int));
    ushort* pkh_all   = (ushort*)alloc((size_t)(8 * 16384 + 49152) * sizeof(ushort));
    ushort* pkl_all   = (ushort*)alloc((size_t)(8 * 16384 + 49152) * sizeof(ushort));
    float* aggA = (float*)alloc((size_t)NN * 128 * sizeof(float));   // hu after GRU
    float* aggB = (float*)alloc((size_t)NN * 128 * sizeof(float));   // hi after GRU

    float* outLo = (float*)d_out;
    float* outHi = outLo + (size_t)NU * 128;

    const int EB = (NE + 255) / 256;

    // ---- CSR build (batched over 4 relations) ----
    hipMemsetAsync(cursor_all, 0, 4 * NN * sizeof(int), stream);
    hipMemsetAsync(rs_src_all, 0, 4 * NN * sizeof(float), stream);
    hist4_kernel<<<dim3(EB, 4), 256, 0, stream>>>(dsts, cursor_all);
    scan_phase_a<<<dim3(NB_SCAN, 4), 256, 0, stream>>>(cursor_all, part);
    scan_phase_b<<<4, 128, 0, stream>>>(part);
    scan_phase_c<<<dim3(NB_SCAN, 4), 256, 0, stream>>>(cursor_all, part, row_ptr_all, rs_dst_all);
    deg4_kernel<<<dim3(EB, 4), 256, 0, stream>>>(srcs, rs_src_all);
    rsqrt_clip_kernel<<<(4 * NN + 255) / 256, 256, 0, stream>>>(rs_src_all, 4 * NN);
    fill4_kernel<<<dim3(EB, 4), 256, 0, stream>>>(srcs, dsts, rs_src_all, cursor_all, col_all, scl_all);

    // ---- pack all weights ----
    pack_all_kernel<<<(8 * 16384 + 49152 + 255) / 256, 256, 0, stream>>>(pw, pkh_all, pkl_all);

    const int GB = (NN + 127) / 128;   // 782
    auto fconv = [&](int r, const float* x, int wi, const float* b, const float* add, float* C) {
        const int* rp = row_ptr_all + r * (NN + 1);
        const int* cl = col_all + (size_t)r * NE;
        const float* sc = scl_all + (size_t)r * NE;
        const float* rd = rs_dst_all + r * NN;
        const ushort* wh = pkh_all + (size_t)wi * 16384;
        const ushort* wl = pkl_all + (size_t)wi * 16384;
        if (add)
            fconv_kernel<true><<<GB, 512, 0, stream>>>(x, rp, cl, sc, rd, wh, wl, b, add, C, NN);
        else
            fconv_kernel<false><<<GB, 512, 0, stream>>>(x, rp, cl, sc, rd, wh, wl, b, nullptr, C, NN);
    };

    // ---- layer 1: hu_pre -> outLo, hi_pre -> outHi ----
    fconv(0, feat_user, 0, b1[0], nullptr, outLo);      // follows
    fconv(2, feat_item, 2, b1[2], outLo, outLo);        // + revbuys (in-place addend)
    fconv(1, feat_user, 1, b1[1], nullptr, outHi);      // buys
    fconv(3, feat_item, 3, b1[3], outHi, outHi);        // + similar

    // ---- GRU (h0 == 0): hu -> aggA, hi -> aggB ----
    const ushort* gwh = pkh_all + (size_t)8 * 16384;
    const ushort* gwl = pkl_all + (size_t)8 * 16384;
    gru_fused_kernel<<<GB, 512, 0, stream>>>(outLo, aggA, gwh, gwl, bih, bhh, NU);
    gru_fused_kernel<<<GB, 512, 0, stream>>>(outHi, aggB, gwh, gwl, bih, bhh, NI);

    // ---- layer 2: read aggA/aggB, write d_out (no aliasing) ----
    fconv(0, aggA, 4, b2[0], nullptr, outLo);           // follows(hu)
    fconv(2, aggB, 6, b2[2], outLo, outLo);             // + revbuys(hi)
    fconv(1, aggA, 5, b2[1], nullptr, outHi);           // buys(hu)
    fconv(3, aggB, 7, b2[3], outHi, outHi);             // + similar(hi)
}

// Round 5
// 516.757 us; speedup vs baseline: 8.2998x; 1.4354x over previous
//
#include <hip/hip_runtime.h>
#include <math.h>

#define NU 100000
#define NI 100000
#define NE 200000
#define NTOT (NU + NI)
#define NN 100000
#define NB_SCAN ((NN + 1023) / 1024)   // 98

typedef __bf16 bf16x8 __attribute__((ext_vector_type(8)));
typedef float f32x4 __attribute__((ext_vector_type(4)));
#define MFMA(a, b, c) __builtin_amdgcn_mfma_f32_16x16x32_bf16(a, b, c, 0, 0, 0)

__device__ __forceinline__ ushort f2bf(float f) {
    uint u = __float_as_uint(f);
    return (ushort)((u + 0x7FFFu + ((u >> 16) & 1u)) >> 16);
}
__device__ __forceinline__ float bf2f(ushort h) {
    return __uint_as_float(((uint)h) << 16);
}

struct Ptr4 { const int* p[4]; };
struct PackW { const float* w[9]; };

// ---------------- histogram: rels 0-3 = dst counts, 4-7 = src counts ----------------
__global__ void hist8_kernel(Ptr4 src, Ptr4 dst, int* __restrict__ cnt) {
    int e = blockIdx.x * blockDim.x + threadIdx.x;
    int r = blockIdx.y;
    if (e < NE) {
        const int* idx = (r < 4) ? dst.p[r] : src.p[r - 4];
        atomicAdd(&cnt[r * NN + idx[e]], 1);
    }
}

__global__ void rsqrt_int_kernel(const int* __restrict__ cnt, float* __restrict__ rs, int n) {
    int t = blockIdx.x * blockDim.x + threadIdx.x;
    if (t < n) rs[t] = rsqrtf(fmaxf((float)cnt[t], 1.0f));
}

// ---------------- exclusive scan (3-phase) over NN ints x 4 rels ----------------
__global__ __launch_bounds__(256) void scan_phase_a(const int* __restrict__ in, int* __restrict__ part) {
    __shared__ int sh[256];
    int rel = blockIdx.y;
    const int* inp = in + rel * NN;
    int tid = threadIdx.x;
    int base = blockIdx.x * 1024 + tid * 4;
    int s = 0;
#pragma unroll
    for (int i = 0; i < 4; i++) { int idx = base + i; if (idx < NN) s += inp[idx]; }
    sh[tid] = s; __syncthreads();
    for (int off = 128; off > 0; off >>= 1) {
        if (tid < off) sh[tid] += sh[tid + off];
        __syncthreads();
    }
    if (tid == 0) part[rel * 128 + blockIdx.x] = sh[0];
}

__global__ void scan_phase_b(int* __restrict__ part) {
    __shared__ int sh[128];
    int rel = blockIdx.x;
    int tid = threadIdx.x;
    int v = (tid < NB_SCAN) ? part[rel * 128 + tid] : 0;
    sh[tid] = v; __syncthreads();
    for (int off = 1; off < 128; off <<= 1) {
        int t = (tid >= off) ? sh[tid - off] : 0;
        __syncthreads();
        sh[tid] += t;
        __syncthreads();
    }
    if (tid < NB_SCAN) part[rel * 128 + tid] = sh[tid] - v;   // exclusive
}

// writes row_ptr, rs_dst, overwrites cnt with start offsets (cursor init)
__global__ __launch_bounds__(256) void scan_phase_c(int* __restrict__ cnt, const int* __restrict__ part,
                                                    int* __restrict__ row_ptr, float* __restrict__ rs) {
    __shared__ int sh[256];
    int rel = blockIdx.y;
    int* inp = cnt + rel * NN;
    int* rp = row_ptr + rel * (NN + 1);
    float* rsd = rs + rel * NN;
    int tid = threadIdx.x;
    int base = blockIdx.x * 1024 + tid * 4;
    int v[4]; int s = 0;
#pragma unroll
    for (int i = 0; i < 4; i++) { int idx = base + i; v[i] = (idx < NN) ? inp[idx] : 0; s += v[i]; }
    sh[tid] = s; __syncthreads();
    for (int off = 1; off < 256; off <<= 1) {
        int t = (tid >= off) ? sh[tid - off] : 0;
        __syncthreads();
        sh[tid] += t;
        __syncthreads();
    }
    int excl = sh[tid] - s + part[rel * 128 + blockIdx.x];
#pragma unroll
    for (int i = 0; i < 4; i++) {
        int idx = base + i;
        if (idx < NN) {
            rp[idx] = excl;
            inp[idx] = excl;                     // cursor init
            rsd[idx] = rsqrtf(fmaxf((float)v[i], 1.0f));
            excl += v[i];
        }
    }
    if (blockIdx.x == 0 && tid == 0) rp[NN] = NE;
}

__global__ void fill4_kernel(Ptr4 src, Ptr4 dst, const float* __restrict__ rs_src,
                             int* __restrict__ cursor, int* __restrict__ col, float* __restrict__ scl) {
    int e = blockIdx.x * blockDim.x + threadIdx.x;
    int r = blockIdx.y;
    if (e >= NE) return;
    int s = src.p[r][e], d = dst.p[r][e];
    int p = atomicAdd(&cursor[r * NN + d], 1);
    col[(size_t)r * NE + p] = s;
    scl[(size_t)r * NE + p] = rs_src[r * NN + s];
}

// ---------------- weight pack ----------------
// pack[((nf*4 + ks)*64 + l)*8 + j] = B[ks*32 + (l>>4)*8 + j][nf*16 + (l&15)]
__global__ void pack_all_kernel(PackW pw, ushort* __restrict__ hi, ushort* __restrict__ lo) {
    int tid = blockIdx.x * blockDim.x + threadIdx.x;
    int wi, local, N, trans;
    if (tid < 8 * 16384) { wi = tid >> 14; local = tid & 16383; N = 128; trans = 0; }
    else {
        int t = tid - 8 * 16384;
        if (t >= 49152) return;
        wi = 8; local = t; N = 384; trans = 1;
    }
    int j = local & 7;
    int l = (local >> 3) & 63;
    int ks = (local >> 9) & 3;
    int nf = local >> 11;
    int k = ks * 32 + ((l >> 4) << 3) + j;
    int n = nf * 16 + (l & 15);
    const float* W = pw.w[wi];
    float v = trans ? W[(size_t)n * 128 + k] : W[(size_t)k * N + n];
    size_t d = (size_t)wi * 16384 + local;
    ushort h = f2bf(v);
    hi[d] = h;
    lo[d] = f2bf(v - bf2f(h));
}

// ---------------- fused dual-relation graph conv ----------------
// C = agg0 @ W0 + agg1 @ W1 + bias0 + bias1, 64 dst rows / block, 512 threads.
__global__ __launch_bounds__(512) void fconv2_kernel(
    const float* __restrict__ x0, const int* __restrict__ rp0, const int* __restrict__ col0,
    const float* __restrict__ scl0, const float* __restrict__ rsd0,
    const ushort* __restrict__ wh0, const ushort* __restrict__ wl0,
    const float* __restrict__ x1, const int* __restrict__ rp1, const int* __restrict__ col1,
    const float* __restrict__ scl1, const float* __restrict__ rsd1,
    const ushort* __restrict__ wh1, const ushort* __restrict__ wl1,
    const float* __restrict__ bias0, const float* __restrict__ bias1,
    float* __restrict__ C, int n) {
    __shared__ __align__(16) ushort Ah[64 * 128];
    __shared__ __align__(16) ushort Al[64 * 128];
    const int tid = threadIdx.x;
    const int row0 = blockIdx.x * 64;

    // ---- gather BOTH relations into registers (max MLP) ----
    const int r = tid >> 3, q = tid & 7;        // 8 threads/row, 16 floats each
    const int d = row0 + r;
    f32x4 g0[4], g1[4];
#pragma unroll
    for (int k = 0; k < 4; k++) { g0[k] = (f32x4)(0.f); g1[k] = (f32x4)(0.f); }
    if (d < n) {
        int j0 = rp0[d], j1 = rp0[d + 1];
        for (int j = j0; j < j1; ++j) {
            int s = col0[j]; float sc = scl0[j];
            const f32x4* xp = (const f32x4*)(x0 + (size_t)s * 128 + q * 16);
#pragma unroll
            for (int k = 0; k < 4; k++) g0[k] += xp[k] * sc;
        }
        float rd = rsd0[d];
#pragma unroll
        for (int k = 0; k < 4; k++) g0[k] *= rd;
        j0 = rp1[d]; j1 = rp1[d + 1];
        for (int j = j0; j < j1; ++j) {
            int s = col1[j]; float sc = scl1[j];
            const f32x4* xp = (const f32x4*)(x1 + (size_t)s * 128 + q * 16);
#pragma unroll
            for (int k = 0; k < 4; k++) g1[k] += xp[k] * sc;
        }
        rd = rsd1[d];
#pragma unroll
        for (int k = 0; k < 4; k++) g1[k] *= rd;
    }

    const int wv = tid >> 6, l = tid & 63;
    const int l15 = l & 15, lh = l >> 4;
    const int rh = wv >> 2, np = wv & 3;

    f32x4 acc[2][2];
#pragma unroll
    for (int m = 0; m < 2; m++)
#pragma unroll
        for (int nfi = 0; nfi < 2; nfi++) acc[m][nfi] = (f32x4)(0.f);

#pragma unroll
    for (int rel = 0; rel < 2; ++rel) {
        // ---- stage split-bf16, swizzled ----
        if (rel) __syncthreads();               // wait for prior MFMA reads
#pragma unroll
        for (int k = 0; k < 4; k++) {
            f32x4 v = rel ? g1[k] : g0[k];
            ushort4 hi, lo;
            hi.x = f2bf(v[0]); lo.x = f2bf(v[0] - bf2f(hi.x));
            hi.y = f2bf(v[1]); lo.y = f2bf(v[1] - bf2f(hi.y));
            hi.z = f2bf(v[2]); lo.z = f2bf(v[2] - bf2f(hi.z));
            hi.w = f2bf(v[3]); lo.w = f2bf(v[3] - bf2f(hi.w));
            int base = (r * 128 + q * 16 + k * 4) ^ ((r & 7) << 3);
            *reinterpret_cast<ushort4*>(&Ah[base]) = hi;
            *reinterpret_cast<ushort4*>(&Al[base]) = lo;
        }
        __syncthreads();

        const ushort* wh = rel ? wh1 : wh0;
        const ushort* wl = rel ? wl1 : wl0;
#pragma unroll
        for (int ks = 0; ks < 4; ++ks) {
            bf16x8 aH[2], aL[2];
#pragma unroll
            for (int m = 0; m < 2; ++m) {
                int row = rh * 32 + m * 16 + l15;
                int idx = (row * 128 + ks * 32 + lh * 8) ^ ((row & 7) << 3);
                aH[m] = *reinterpret_cast<const bf16x8*>(&Ah[idx]);
                aL[m] = *reinterpret_cast<const bf16x8*>(&Al[idx]);
            }
#pragma unroll
            for (int nfi = 0; nfi < 2; ++nfi) {
                int nf = np * 2 + nfi;
                size_t off = ((size_t)(nf * 4 + ks) * 64 + l) * 8;
                bf16x8 bH = *reinterpret_cast<const bf16x8*>(wh + off);
                bf16x8 bL = *reinterpret_cast<const bf16x8*>(wl + off);
#pragma unroll
                for (int m = 0; m < 2; ++m) {
                    acc[m][nfi] = MFMA(aH[m], bH, acc[m][nfi]);
                    acc[m][nfi] = MFMA(aL[m], bH, acc[m][nfi]);
                    acc[m][nfi] = MFMA(aH[m], bL, acc[m][nfi]);
                }
            }
        }
    }

    // ---- epilogue ----
#pragma unroll
    for (int m = 0; m < 2; ++m) {
        int rbase = row0 + rh * 32 + m * 16 + lh * 4;
#pragma unroll
        for (int nfi = 0; nfi < 2; ++nfi) {
            int c = (np * 2 + nfi) * 16 + l15;
            float bs = bias0[c] + bias1[c];
#pragma unroll
            for (int i = 0; i < 4; ++i) {
                int gr = rbase + i;
                if (gr < n) C[(size_t)gr * 128 + c] = acc[m][nfi][i] + bs;
            }
        }
    }
}

// ---------------- fused GRU (h0 == 0): out = (1-z)*tanh(in + r*bhh_n) ----------------
// 64 rows/block, ks-outer loop, all 3 gate accumulators live.
__global__ __launch_bounds__(512) void gru_fused_kernel(
    const float* __restrict__ X, float* __restrict__ out,
    const ushort* __restrict__ wh, const ushort* __restrict__ wl,
    const float* __restrict__ bih, const float* __restrict__ bhh, int M) {
    __shared__ __align__(16) ushort Ah[64 * 128];
    __shared__ __align__(16) ushort Al[64 * 128];
    const int tid = threadIdx.x;
    const int row0 = blockIdx.x * 64;

    // ---- stage relu(X) -> split bf16 -> LDS ----
    {
        const int r = tid >> 3, q = tid & 7;
        const int gr = row0 + r;
        const f32x4* xp = (const f32x4*)(X + (size_t)gr * 128 + q * 16);
#pragma unroll
        for (int k = 0; k < 4; ++k) {
            f32x4 v = (gr < M) ? xp[k] : (f32x4)(0.f);
            ushort4 hi, lo;
            float e;
            e = fmaxf(v[0], 0.f); hi.x = f2bf(e); lo.x = f2bf(e - bf2f(hi.x));
            e = fmaxf(v[1], 0.f); hi.y = f2bf(e); lo.y = f2bf(e - bf2f(hi.y));
            e = fmaxf(v[2], 0.f); hi.z = f2bf(e); lo.z = f2bf(e - bf2f(hi.z));
            e = fmaxf(v[3], 0.f); hi.w = f2bf(e); lo.w = f2bf(e - bf2f(hi.w));
            int base = (r * 128 + q * 16 + k * 4) ^ ((r & 7) << 3);
            *reinterpret_cast<ushort4*>(&Ah[base]) = hi;
            *reinterpret_cast<ushort4*>(&Al[base]) = lo;
        }
    }
    __syncthreads();

    const int wv = tid >> 6, l = tid & 63;
    const int l15 = l & 15, lh = l >> 4;
    const int rh = wv >> 2, np = wv & 3;

    f32x4 acc[3][2][2];
#pragma unroll
    for (int g = 0; g < 3; g++)
#pragma unroll
        for (int m = 0; m < 2; m++)
#pragma unroll
            for (int nfi = 0; nfi < 2; nfi++) acc[g][m][nfi] = (f32x4)(0.f);

#pragma unroll
    for (int ks = 0; ks < 4; ++ks) {
        bf16x8 aH[2], aL[2];
#pragma unroll
        for (int m = 0; m < 2; ++m) {
            int row = rh * 32 + m * 16 + l15;
            int idx = (row * 128 + ks * 32 + lh * 8) ^ ((row & 7) << 3);
            aH[m] = *reinterpret_cast<const bf16x8*>(&Ah[idx]);
            aL[m] = *reinterpret_cast<const bf16x8*>(&Al[idx]);
        }
#pragma unroll
        for (int g = 0; g < 3; ++g) {
#pragma unroll
            for (int nfi = 0; nfi < 2; ++nfi) {
                int gnf = g * 8 + np * 2 + nfi;
                size_t off = ((size_t)(gnf * 4 + ks) * 64 + l) * 8;
                bf16x8 bH = *reinterpret_cast<const bf16x8*>(wh + off);
                bf16x8 bL = *reinterpret_cast<const bf16x8*>(wl + off);
#pragma unroll
                for (int m = 0; m < 2; ++m) {
                    acc[g][m][nfi] = MFMA(aH[m], bH, acc[g][m][nfi]);
                    acc[g][m][nfi] = MFMA(aL[m], bH, acc[g][m][nfi]);
                    acc[g][m][nfi] = MFMA(aH[m], bL, acc[g][m][nfi]);
                }
            }
        }
    }

    // ---- epilogue: gates inline ----
#pragma unroll
    for (int m = 0; m < 2; ++m) {
        int rbase = row0 + rh * 32 + m * 16 + lh * 4;
#pragma unroll
        for (int nfi = 0; nfi < 2; ++nfi) {
            int c = (np * 2 + nfi) * 16 + l15;
            float b0 = bih[c] + bhh[c];
            float b1 = bih[128 + c] + bhh[128 + c];
            float b2i = bih[256 + c], b2h = bhh[256 + c];
#pragma unroll
            for (int i = 0; i < 4; ++i) {
                int gr = rbase + i;
                if (gr < M) {
                    float rr = 1.f / (1.f + expf(-(acc[0][m][nfi][i] + b0)));
                    float zz = 1.f / (1.f + expf(-(acc[1][m][nfi][i] + b1)));
                    float nn = tanhf(acc[2][m][nfi][i] + b2i + rr * b2h);
                    out[(size_t)gr * 128 + c] = (1.f - zz) * nn;
                }
            }
        }
    }
}

// ---------------- launch ----------------
extern "C" void kernel_launch(void* const* d_in, const int* in_sizes, int n_in,
                              void* d_out, int out_size, void* d_ws, size_t ws_size,
                              hipStream_t stream) {
    const float* feat_user = (const float*)d_in[0];
    const float* feat_item = (const float*)d_in[1];

    // relation order: 0=follows(U->U) 1=buys(U->I) 2=revbuys(I->U) 3=similar(I->I)
    Ptr4 srcs = {{(const int*)d_in[3], (const int*)d_in[9], (const int*)d_in[15], (const int*)d_in[21]}};
    Ptr4 dsts = {{(const int*)d_in[4], (const int*)d_in[10], (const int*)d_in[16], (const int*)d_in[22]}};
    const float* b1[4] = {(const float*)d_in[6],  (const float*)d_in[12], (const float*)d_in[18], (const float*)d_in[24]};
    const float* b2[4] = {(const float*)d_in[8],  (const float*)d_in[14], (const float*)d_in[20], (const float*)d_in[26]};

    PackW pw = {{(const float*)d_in[5], (const float*)d_in[11], (const float*)d_in[17], (const float*)d_in[23],
                 (const float*)d_in[7], (const float*)d_in[13], (const float*)d_in[19], (const float*)d_in[25],
                 (const float*)d_in[27]}};
    const float* bih = (const float*)d_in[29];
    const float* bhh = (const float*)d_in[30];

    // ---- workspace layout ----
    char* w = (char*)d_ws;
    auto alloc = [&](size_t bytes) { char* r = w; w += (bytes + 255) & ~(size_t)255; return r; };
    int* cnt8          = (int*)alloc(8 * NN * sizeof(int));      // rels 0-3: dst cnt->cursor; 4-7: src cnt
    float* rs_src_all  = (float*)alloc(4 * NN * sizeof(float));
    float* rs_dst_all  = (float*)alloc(4 * NN * sizeof(float));
    int* row_ptr_all   = (int*)alloc(4 * (NN + 1) * sizeof(int));
    int* col_all       = (int*)alloc((size_t)4 * NE * sizeof(int));
    float* scl_all     = (float*)alloc((size_t)4 * NE * sizeof(float));
    int* part          = (int*)alloc(4 * 128 * sizeof(int));
    ushort* pkh_all    = (ushort*)alloc((size_t)(8 * 16384 + 49152) * sizeof(ushort));
    ushort* pkl_all    = (ushort*)alloc((size_t)(8 * 16384 + 49152) * sizeof(ushort));
    float* hbuf        = (float*)alloc((size_t)NTOT * 128 * sizeof(float));   // hc after GRU

    float* outLo = (float*)d_out;
    float* outHi = outLo + (size_t)NU * 128;
    float* hu = hbuf;
    float* hi = hbuf + (size_t)NU * 128;

    const int EB = (NE + 255) / 256;

    // ---- CSR build ----
    hipMemsetAsync(cnt8, 0, 8 * NN * sizeof(int), stream);
    hist8_kernel<<<dim3(EB, 8), 256, 0, stream>>>(srcs, dsts, cnt8);
    scan_phase_a<<<dim3(NB_SCAN, 4), 256, 0, stream>>>(cnt8, part);
    scan_phase_b<<<4, 128, 0, stream>>>(part);
    scan_phase_c<<<dim3(NB_SCAN, 4), 256, 0, stream>>>(cnt8, part, row_ptr_all, rs_dst_all);
    rsqrt_int_kernel<<<(4 * NN + 255) / 256, 256, 0, stream>>>(cnt8 + 4 * NN, rs_src_all, 4 * NN);
    fill4_kernel<<<dim3(EB, 4), 256, 0, stream>>>(srcs, dsts, rs_src_all, cnt8, col_all, scl_all);

    // ---- pack all weights ----
    pack_all_kernel<<<(8 * 16384 + 49152 + 255) / 256, 256, 0, stream>>>(pw, pkh_all, pkl_all);

    const int GB = (NN + 63) / 64;   // 1563
    auto fconv2 = [&](int rA, const float* xA, int wA, const float* bA,
                      int rB, const float* xB, int wB, const float* bB, float* C) {
        fconv2_kernel<<<GB, 512, 0, stream>>>(
            xA, row_ptr_all + rA * (NN + 1), col_all + (size_t)rA * NE,
            scl_all + (size_t)rA * NE, rs_dst_all + rA * NN,
            pkh_all + (size_t)wA * 16384, pkl_all + (size_t)wA * 16384,
            xB, row_ptr_all + rB * (NN + 1), col_all + (size_t)rB * NE,
            scl_all + (size_t)rB * NE, rs_dst_all + rB * NN,
            pkh_all + (size_t)wB * 16384, pkl_all + (size_t)wB * 16384,
            bA, bB, C, NN);
    };

    // ---- layer 1: hu_pre -> outLo, hi_pre -> outHi ----
    fconv2(0, feat_user, 0, b1[0], 2, feat_item, 2, b1[2], outLo);
    fconv2(1, feat_user, 1, b1[1], 3, feat_item, 3, b1[3], outHi);

    // ---- GRU (h0 == 0) over all NTOT rows: d_out -> hbuf ----
    const ushort* gwh = pkh_all + (size_t)8 * 16384;
    const ushort* gwl = pkl_all + (size_t)8 * 16384;
    gru_fused_kernel<<<(NTOT + 63) / 64, 512, 0, stream>>>(outLo, hbuf, gwh, gwl, bih, bhh, NTOT);

    // ---- layer 2: read hbuf, write d_out ----
    fconv2(0, hu, 4, b2[0], 2, hi, 6, b2[2], outLo);   // ou
    fconv2(1, hu, 5, b2[1], 3, hi, 7, b2[3], outHi);   // oi
}

// Round 6
// 440.726 us; speedup vs baseline: 9.7316x; 1.1725x over previous
//
#include <hip/hip_runtime.h>
#include <math.h>

#define NU 100000
#define NI 100000
#define NE 200000
#define NTOT (NU + NI)
#define NN 100000
#define NB_SCAN ((NN + 1023) / 1024)   // 98

typedef __bf16 bf16x8 __attribute__((ext_vector_type(8)));
typedef float f32x4 __attribute__((ext_vector_type(4)));
typedef ushort us8 __attribute__((ext_vector_type(8)));
#define MFMA(a, b, c) __builtin_amdgcn_mfma_f32_16x16x32_bf16(a, b, c, 0, 0, 0)

__device__ __forceinline__ ushort f2bf(float f) {
    uint u = __float_as_uint(f);
    return (ushort)((u + 0x7FFFu + ((u >> 16) & 1u)) >> 16);
}
__device__ __forceinline__ float bf2f(ushort h) {
    return __uint_as_float(((uint)h) << 16);
}
__device__ __forceinline__ float fsig(float x) { return 1.f / (1.f + __expf(-x)); }
__device__ __forceinline__ float ftanh(float x) { return 1.f - 2.f / (1.f + __expf(2.f * x)); }

struct Ptr4 { const int* p[4]; };
struct PackW { const float* w[9]; };
struct Rel {
    const int* rp; const int2* edge; const float* rsd;
    const ushort* wh; const ushort* wl; const float* bias;
};

// ---------------- histogram: rels 0-3 = dst counts, 4-7 = src counts ----------------
__global__ void hist8_kernel(Ptr4 src, Ptr4 dst, int* __restrict__ cnt) {
    int e = blockIdx.x * blockDim.x + threadIdx.x;
    int r = blockIdx.y;
    if (e < NE) {
        const int* idx = (r < 4) ? dst.p[r] : src.p[r - 4];
        atomicAdd(&cnt[r * NN + idx[e]], 1);
    }
}

__global__ void rsqrt_int_kernel(const int* __restrict__ cnt, float* __restrict__ rs, int n) {
    int t = blockIdx.x * blockDim.x + threadIdx.x;
    if (t < n) rs[t] = rsqrtf(fmaxf((float)cnt[t], 1.0f));
}

// ---------------- exclusive scan (3-phase) over NN ints x 4 rels ----------------
__global__ __launch_bounds__(256) void scan_phase_a(const int* __restrict__ in, int* __restrict__ part) {
    __shared__ int sh[256];
    int rel = blockIdx.y;
    const int* inp = in + rel * NN;
    int tid = threadIdx.x;
    int base = blockIdx.x * 1024 + tid * 4;
    int s = 0;
#pragma unroll
    for (int i = 0; i < 4; i++) { int idx = base + i; if (idx < NN) s += inp[idx]; }
    sh[tid] = s; __syncthreads();
    for (int off = 128; off > 0; off >>= 1) {
        if (tid < off) sh[tid] += sh[tid + off];
        __syncthreads();
    }
    if (tid == 0) part[rel * 128 + blockIdx.x] = sh[0];
}

__global__ void scan_phase_b(int* __restrict__ part) {
    __shared__ int sh[128];
    int rel = blockIdx.x;
    int tid = threadIdx.x;
    int v = (tid < NB_SCAN) ? part[rel * 128 + tid] : 0;
    sh[tid] = v; __syncthreads();
    for (int off = 1; off < 128; off <<= 1) {
        int t = (tid >= off) ? sh[tid - off] : 0;
        __syncthreads();
        sh[tid] += t;
        __syncthreads();
    }
    if (tid < NB_SCAN) part[rel * 128 + tid] = sh[tid] - v;   // exclusive
}

__global__ __launch_bounds__(256) void scan_phase_c(int* __restrict__ cnt, const int* __restrict__ part,
                                                    int* __restrict__ row_ptr, float* __restrict__ rs) {
    __shared__ int sh[256];
    int rel = blockIdx.y;
    int* inp = cnt + rel * NN;
    int* rp = row_ptr + rel * (NN + 1);
    float* rsd = rs + rel * NN;
    int tid = threadIdx.x;
    int base = blockIdx.x * 1024 + tid * 4;
    int v[4]; int s = 0;
#pragma unroll
    for (int i = 0; i < 4; i++) { int idx = base + i; v[i] = (idx < NN) ? inp[idx] : 0; s += v[i]; }
    sh[tid] = s; __syncthreads();
    for (int off = 1; off < 256; off <<= 1) {
        int t = (tid >= off) ? sh[tid - off] : 0;
        __syncthreads();
        sh[tid] += t;
        __syncthreads();
    }
    int excl = sh[tid] - s + part[rel * 128 + blockIdx.x];
#pragma unroll
    for (int i = 0; i < 4; i++) {
        int idx = base + i;
        if (idx < NN) {
            rp[idx] = excl;
            inp[idx] = excl;                     // cursor init
            rsd[idx] = rsqrtf(fmaxf((float)v[i], 1.0f));
            excl += v[i];
        }
    }
    if (blockIdx.x == 0 && tid == 0) rp[NN] = NE;
}

__global__ void fill4_kernel(Ptr4 src, Ptr4 dst, const float* __restrict__ rs_src,
                             int* __restrict__ cursor, int2* __restrict__ edge) {
    int e = blockIdx.x * blockDim.x + threadIdx.x;
    int r = blockIdx.y;
    if (e >= NE) return;
    int s = src.p[r][e], d = dst.p[r][e];
    int p = atomicAdd(&cursor[r * NN + d], 1);
    edge[(size_t)r * NE + p] = make_int2(s, __float_as_int(rs_src[r * NN + s]));
}

// ---------------- weight pack ----------------
// pack[((nf*4 + ks)*64 + l)*8 + j] = B[ks*32 + (l>>4)*8 + j][nf*16 + (l&15)]
__global__ void pack_all_kernel(PackW pw, ushort* __restrict__ hi, ushort* __restrict__ lo) {
    int tid = blockIdx.x * blockDim.x + threadIdx.x;
    int wi, local, N, trans;
    if (tid < 8 * 16384) { wi = tid >> 14; local = tid & 16383; N = 128; trans = 0; }
    else {
        int t = tid - 8 * 16384;
        if (t >= 49152) return;
        wi = 8; local = t; N = 384; trans = 1;
    }
    int j = local & 7;
    int l = (local >> 3) & 63;
    int ks = (local >> 9) & 3;
    int nf = local >> 11;
    int k = ks * 32 + ((l >> 4) << 3) + j;
    int n = nf * 16 + (l & 15);
    const float* W = pw.w[wi];
    float v = trans ? W[(size_t)n * 128 + k] : W[(size_t)k * N + n];
    size_t d = (size_t)wi * 16384 + local;
    ushort h = f2bf(v);
    hi[d] = h;
    lo[d] = f2bf(v - bf2f(h));
}

// ---------------- feats -> bf16 ----------------
__global__ __launch_bounds__(256) void tobf_kernel(const float* __restrict__ a, const float* __restrict__ b,
                                                   ushort* __restrict__ o) {
    size_t i = ((size_t)blockIdx.x * blockDim.x + threadIdx.x) * 8;
    if (i >= (size_t)NN * 128) return;
    const float* src = blockIdx.y ? b : a;
    ushort* dst = o + (blockIdx.y ? (size_t)NU * 128 : 0);
    f32x4 v0 = *(const f32x4*)(src + i);
    f32x4 v1 = *(const f32x4*)(src + i + 4);
    us8 r;
#pragma unroll
    for (int j = 0; j < 4; j++) r[j] = f2bf(v0[j]);
#pragma unroll
    for (int j = 0; j < 4; j++) r[4 + j] = f2bf(v1[j]);
    *(us8*)(dst + i) = r;
}

// ---------------- fused dual-relation conv (+optional GRU epilogue) ----------------
// 64 dst rows/block, 512 threads. x is bf16 (row stride 128).
// GRU_EPI: v = relu(conv+biases); gi = v@wih^T; gates (gh = bhh, h0 = 0); H = (1-z)*tanh(...)
template <bool GRU_EPI>
__global__ __launch_bounds__(512) void fused_kernel(
    const ushort* __restrict__ x0, const ushort* __restrict__ x1,
    Rel A0, Rel B0, Rel A1, Rel B1,
    const ushort* __restrict__ gwh, const ushort* __restrict__ gwl,
    const float* __restrict__ bih, const float* __restrict__ bhh,
    float* __restrict__ C0, float* __restrict__ C1,
    ushort* __restrict__ H0, ushort* __restrict__ H1, int n) {
    __shared__ __align__(16) ushort Ah[64 * 128];
    __shared__ __align__(16) ushort Al[64 * 128];
    const Rel A = blockIdx.y ? A1 : A0;
    const Rel B = blockIdx.y ? B1 : B0;
    const int tid = threadIdx.x;
    const int row0 = blockIdx.x * 64;

    // ---- gather BOTH relations into registers ----
    const int r = tid >> 3, q = tid & 7;        // 8 threads/row, 16 bf16 each
    const int d = row0 + r;
    f32x4 gA[4], gB[4];
#pragma unroll
    for (int k = 0; k < 4; k++) { gA[k] = (f32x4)(0.f); gB[k] = (f32x4)(0.f); }
    if (d < n) {
        int j0 = A.rp[d], j1 = A.rp[d + 1];
        for (int j = j0; j < j1; ++j) {
            int2 e = A.edge[j];
            float sc = __int_as_float(e.y);
            const us8* xp = (const us8*)(x0 + (size_t)e.x * 128 + q * 16);
            us8 v0 = xp[0], v1 = xp[1];
#pragma unroll
            for (int t = 0; t < 8; ++t) gA[t >> 2][t & 3] = fmaf(bf2f(v0[t]), sc, gA[t >> 2][t & 3]);
#pragma unroll
            for (int t = 0; t < 8; ++t) gA[2 + (t >> 2)][t & 3] = fmaf(bf2f(v1[t]), sc, gA[2 + (t >> 2)][t & 3]);
        }
        float rd = A.rsd[d];
#pragma unroll
        for (int k = 0; k < 4; k++) gA[k] *= rd;
        j0 = B.rp[d]; j1 = B.rp[d + 1];
        for (int j = j0; j < j1; ++j) {
            int2 e = B.edge[j];
            float sc = __int_as_float(e.y);
            const us8* xp = (const us8*)(x1 + (size_t)e.x * 128 + q * 16);
            us8 v0 = xp[0], v1 = xp[1];
#pragma unroll
            for (int t = 0; t < 8; ++t) gB[t >> 2][t & 3] = fmaf(bf2f(v0[t]), sc, gB[t >> 2][t & 3]);
#pragma unroll
            for (int t = 0; t < 8; ++t) gB[2 + (t >> 2)][t & 3] = fmaf(bf2f(v1[t]), sc, gB[2 + (t >> 2)][t & 3]);
        }
        rd = B.rsd[d];
#pragma unroll
        for (int k = 0; k < 4; k++) gB[k] *= rd;
    }

    const int wv = tid >> 6, l = tid & 63;
    const int l15 = l & 15, lh = l >> 4;
    const int rh = wv >> 2, np = wv & 3;

    f32x4 acc[2][2];
#pragma unroll
    for (int m = 0; m < 2; m++)
#pragma unroll
        for (int nfi = 0; nfi < 2; nfi++) acc[m][nfi] = (f32x4)(0.f);

#pragma unroll
    for (int rel = 0; rel < 2; ++rel) {
        if (rel) __syncthreads();
#pragma unroll
        for (int k = 0; k < 4; k++) {
            f32x4 v = rel ? gB[k] : gA[k];
            ushort4 hi, lo;
            hi.x = f2bf(v[0]); lo.x = f2bf(v[0] - bf2f(hi.x));
            hi.y = f2bf(v[1]); lo.y = f2bf(v[1] - bf2f(hi.y));
            hi.z = f2bf(v[2]); lo.z = f2bf(v[2] - bf2f(hi.z));
            hi.w = f2bf(v[3]); lo.w = f2bf(v[3] - bf2f(hi.w));
            int base = (r * 128 + q * 16 + k * 4) ^ ((r & 7) << 3);
            *reinterpret_cast<ushort4*>(&Ah[base]) = hi;
            *reinterpret_cast<ushort4*>(&Al[base]) = lo;
        }
        __syncthreads();

        const ushort* wh = rel ? B.wh : A.wh;
        const ushort* wl = rel ? B.wl : A.wl;
#pragma unroll
        for (int ks = 0; ks < 4; ++ks) {
            bf16x8 aH[2], aL[2];
#pragma unroll
            for (int m = 0; m < 2; ++m) {
                int row = rh * 32 + m * 16 + l15;
                int idx = (row * 128 + ks * 32 + lh * 8) ^ ((row & 7) << 3);
                aH[m] = *reinterpret_cast<const bf16x8*>(&Ah[idx]);
                aL[m] = *reinterpret_cast<const bf16x8*>(&Al[idx]);
            }
#pragma unroll
            for (int nfi = 0; nfi < 2; ++nfi) {
                int nf = np * 2 + nfi;
                size_t off = ((size_t)(nf * 4 + ks) * 64 + l) * 8;
                bf16x8 bH = *reinterpret_cast<const bf16x8*>(wh + off);
                bf16x8 bL = *reinterpret_cast<const bf16x8*>(wl + off);
#pragma unroll
                for (int m = 0; m < 2; ++m) {
                    acc[m][nfi] = MFMA(aH[m], bH, acc[m][nfi]);
                    acc[m][nfi] = MFMA(aL[m], bH, acc[m][nfi]);
                    acc[m][nfi] = MFMA(aH[m], bL, acc[m][nfi]);
                }
            }
        }
    }

    if (!GRU_EPI) {
        float* C = blockIdx.y ? C1 : C0;
#pragma unroll
        for (int m = 0; m < 2; ++m) {
            int rbase = row0 + rh * 32 + m * 16 + lh * 4;
#pragma unroll
            for (int nfi = 0; nfi < 2; ++nfi) {
                int c = (np * 2 + nfi) * 16 + l15;
                float bs = A.bias[c] + B.bias[c];
#pragma unroll
                for (int i = 0; i < 4; ++i) {
                    int gr = rbase + i;
                    if (gr < n) C[(size_t)gr * 128 + c] = acc[m][nfi][i] + bs;
                }
            }
        }
        return;
    }

    // ---- phase C: relu(conv) -> split bf16 back into LDS (fragment positions) ----
    __syncthreads();                             // all phase-B LDS reads done
#pragma unroll
    for (int m = 0; m < 2; ++m) {
#pragma unroll
        for (int nfi = 0; nfi < 2; ++nfi) {
            int c = (np * 2 + nfi) * 16 + l15;
            float bs = A.bias[c] + B.bias[c];
#pragma unroll
            for (int i = 0; i < 4; ++i) {
                int rr = rh * 32 + m * 16 + lh * 4 + i;
                float v = fmaxf(acc[m][nfi][i] + bs, 0.f);
                ushort hi = f2bf(v);
                int idx = (rr * 128 + c) ^ ((rr & 7) << 3);
                Ah[idx] = hi;
                Al[idx] = f2bf(v - bf2f(hi));
            }
        }
    }
    __syncthreads();

    // ---- phase D: gi = x @ wih^T (3 gates), all accumulators live ----
    f32x4 g3[3][2][2];
#pragma unroll
    for (int g = 0; g < 3; g++)
#pragma unroll
        for (int m = 0; m < 2; m++)
#pragma unroll
            for (int nfi = 0; nfi < 2; nfi++) g3[g][m][nfi] = (f32x4)(0.f);

#pragma unroll
    for (int ks = 0; ks < 4; ++ks) {
        bf16x8 aH[2], aL[2];
#pragma unroll
        for (int m = 0; m < 2; ++m) {
            int row = rh * 32 + m * 16 + l15;
            int idx = (row * 128 + ks * 32 + lh * 8) ^ ((row & 7) << 3);
            aH[m] = *reinterpret_cast<const bf16x8*>(&Ah[idx]);
            aL[m] = *reinterpret_cast<const bf16x8*>(&Al[idx]);
        }
#pragma unroll
        for (int g = 0; g < 3; ++g) {
#pragma unroll
            for (int nfi = 0; nfi < 2; ++nfi) {
                int gnf = g * 8 + np * 2 + nfi;
                size_t off = ((size_t)(gnf * 4 + ks) * 64 + l) * 8;
                bf16x8 bH = *reinterpret_cast<const bf16x8*>(gwh + off);
                bf16x8 bL = *reinterpret_cast<const bf16x8*>(gwl + off);
#pragma unroll
                for (int m = 0; m < 2; ++m) {
                    g3[g][m][nfi] = MFMA(aH[m], bH, g3[g][m][nfi]);
                    g3[g][m][nfi] = MFMA(aL[m], bH, g3[g][m][nfi]);
                    g3[g][m][nfi] = MFMA(aH[m], bL, g3[g][m][nfi]);
                }
            }
        }
    }

    // ---- phase E: gates, write bf16 h ----
    ushort* H = blockIdx.y ? H1 : H0;
#pragma unroll
    for (int m = 0; m < 2; ++m) {
        int rbase = row0 + rh * 32 + m * 16 + lh * 4;
#pragma unroll
        for (int nfi = 0; nfi < 2; ++nfi) {
            int c = (np * 2 + nfi) * 16 + l15;
            float b0 = bih[c] + bhh[c];
            float b1 = bih[128 + c] + bhh[128 + c];
            float b2i = bih[256 + c], b2h = bhh[256 + c];
#pragma unroll
            for (int i = 0; i < 4; ++i) {
                int gr = rbase + i;
                if (gr < n) {
                    float rr = fsig(g3[0][m][nfi][i] + b0);
                    float zz = fsig(g3[1][m][nfi][i] + b1);
                    float nn = ftanh(g3[2][m][nfi][i] + b2i + rr * b2h);
                    H[(size_t)gr * 128 + c] = f2bf((1.f - zz) * nn);
                }
            }
        }
    }
}

// ---------------- launch ----------------
extern "C" void kernel_launch(void* const* d_in, const int* in_sizes, int n_in,
                              void* d_out, int out_size, void* d_ws, size_t ws_size,
                              hipStream_t stream) {
    const float* feat_user = (const float*)d_in[0];
    const float* feat_item = (const float*)d_in[1];

    // relation order: 0=follows(U->U) 1=buys(U->I) 2=revbuys(I->U) 3=similar(I->I)
    Ptr4 srcs = {{(const int*)d_in[3], (const int*)d_in[9], (const int*)d_in[15], (const int*)d_in[21]}};
    Ptr4 dsts = {{(const int*)d_in[4], (const int*)d_in[10], (const int*)d_in[16], (const int*)d_in[22]}};
    const float* b1[4] = {(const float*)d_in[6],  (const float*)d_in[12], (const float*)d_in[18], (const float*)d_in[24]};
    const float* b2[4] = {(const float*)d_in[8],  (const float*)d_in[14], (const float*)d_in[20], (const float*)d_in[26]};

    PackW pw = {{(const float*)d_in[5], (const float*)d_in[11], (const float*)d_in[17], (const float*)d_in[23],
                 (const float*)d_in[7], (const float*)d_in[13], (const float*)d_in[19], (const float*)d_in[25],
                 (const float*)d_in[27]}};
    const float* bih = (const float*)d_in[29];
    const float* bhh = (const float*)d_in[30];

    // ---- workspace ----
    char* w = (char*)d_ws;
    auto alloc = [&](size_t bytes) { char* r = w; w += (bytes + 255) & ~(size_t)255; return r; };
    int* cnt8         = (int*)alloc(8 * NN * sizeof(int));
    float* rs_src_all = (float*)alloc(4 * NN * sizeof(float));
    float* rs_dst_all = (float*)alloc(4 * NN * sizeof(float));
    int* row_ptr_all  = (int*)alloc(4 * (NN + 1) * sizeof(int));
    int2* edge_all    = (int2*)alloc((size_t)4 * NE * sizeof(int2));
    int* part         = (int*)alloc(4 * 128 * sizeof(int));
    ushort* pkh_all   = (ushort*)alloc((size_t)(8 * 16384 + 49152) * sizeof(ushort));
    ushort* pkl_all   = (ushort*)alloc((size_t)(8 * 16384 + 49152) * sizeof(ushort));
    ushort* featbf    = (ushort*)alloc((size_t)NTOT * 128 * sizeof(ushort));
    ushort* hbuf      = (ushort*)alloc((size_t)NTOT * 128 * sizeof(ushort));

    float* outLo = (float*)d_out;
    float* outHi = outLo + (size_t)NU * 128;
    const ushort* featu = featbf;
    const ushort* feati = featbf + (size_t)NU * 128;
    ushort* hu = hbuf;
    ushort* hi = hbuf + (size_t)NU * 128;

    const int EB = (NE + 255) / 256;

    // ---- CSR build ----
    hipMemsetAsync(cnt8, 0, 8 * NN * sizeof(int), stream);
    hist8_kernel<<<dim3(EB, 8), 256, 0, stream>>>(srcs, dsts, cnt8);
    scan_phase_a<<<dim3(NB_SCAN, 4), 256, 0, stream>>>(cnt8, part);
    scan_phase_b<<<4, 128, 0, stream>>>(part);
    scan_phase_c<<<dim3(NB_SCAN, 4), 256, 0, stream>>>(cnt8, part, row_ptr_all, rs_dst_all);
    rsqrt_int_kernel<<<(4 * NN + 255) / 256, 256, 0, stream>>>(cnt8 + 4 * NN, rs_src_all, 4 * NN);
    fill4_kernel<<<dim3(EB, 4), 256, 0, stream>>>(srcs, dsts, rs_src_all, cnt8, edge_all);

    // ---- pack weights + convert feats ----
    pack_all_kernel<<<(8 * 16384 + 49152 + 255) / 256, 256, 0, stream>>>(pw, pkh_all, pkl_all);
    tobf_kernel<<<dim3((NN * 128 / 8 + 255) / 256, 2), 256, 0, stream>>>(feat_user, feat_item, featbf);

    auto mkrel = [&](int r, int wi, const float* bias) {
        Rel R;
        R.rp = row_ptr_all + r * (NN + 1);
        R.edge = edge_all + (size_t)r * NE;
        R.rsd = rs_dst_all + r * NN;
        R.wh = pkh_all + (size_t)wi * 16384;
        R.wl = pkl_all + (size_t)wi * 16384;
        R.bias = bias;
        return R;
    };
    const ushort* gwh = pkh_all + (size_t)8 * 16384;
    const ushort* gwl = pkl_all + (size_t)8 * 16384;
    const int GB = (NN + 63) / 64;   // 1563

    // ---- layer 1 + GRU: feats -> h (bf16), one dispatch ----
    fused_kernel<true><<<dim3(GB, 2), 512, 0, stream>>>(
        featu, feati,
        mkrel(0, 0, b1[0]), mkrel(2, 2, b1[2]),    // y=0: follows + revbuys -> hu
        mkrel(1, 1, b1[1]), mkrel(3, 3, b1[3]),    // y=1: buys + similar   -> hi
        gwh, gwl, bih, bhh, nullptr, nullptr, hu, hi, NN);

    // ---- layer 2: h -> d_out, one dispatch ----
    fused_kernel<false><<<dim3(GB, 2), 512, 0, stream>>>(
        hu, hi,
        mkrel(0, 4, b2[0]), mkrel(2, 6, b2[2]),    // y=0: ou
        mkrel(1, 5, b2[1]), mkrel(3, 7, b2[3]),    // y=1: oi
        gwh, gwl, bih, bhh, outLo, outHi, nullptr, nullptr, NN);
}

// Round 7
// 420.564 us; speedup vs baseline: 10.1981x; 1.0479x over previous
//
#include <hip/hip_runtime.h>
#include <math.h>

#define NU 100000
#define NI 100000
#define NE 200000
#define NTOT (NU + NI)
#define NN 100000
#define NB_SCAN ((NN + 1023) / 1024)   // 98

typedef __bf16 bf16x8 __attribute__((ext_vector_type(8)));
typedef float f32x4 __attribute__((ext_vector_type(4)));
#define MFMA(a, b, c) __builtin_amdgcn_mfma_f32_16x16x32_bf16(a, b, c, 0, 0, 0)

__device__ __forceinline__ ushort f2bf(float f) {
    uint u = __float_as_uint(f);
    return (ushort)((u + 0x7FFFu + ((u >> 16) & 1u)) >> 16);
}
__device__ __forceinline__ float bf2f(ushort h) {
    return __uint_as_float(((uint)h) << 16);
}
__device__ __forceinline__ float fsig(float x) { return 1.f / (1.f + __expf(-x)); }
__device__ __forceinline__ float ftanh(float x) { return 1.f - 2.f / (1.f + __expf(2.f * x)); }

struct Ptr4 { const int* p[4]; };
struct PackW { const float* w[9]; };
struct Rel {
    const int* rp; const int2* edge; const float* rsd;
    const ushort* wh; const ushort* wl; const float* bias;
};

// ---------------- histogram: rels 0-3 = dst counts, 4-7 = src counts ----------------
__global__ void hist8_kernel(Ptr4 src, Ptr4 dst, int* __restrict__ cnt) {
    int e = blockIdx.x * blockDim.x + threadIdx.x;
    int r = blockIdx.y;
    if (e < NE) {
        const int* idx = (r < 4) ? dst.p[r] : src.p[r - 4];
        atomicAdd(&cnt[r * NN + idx[e]], 1);
    }
}

__global__ void rsqrt_int_kernel(const int* __restrict__ cnt, float* __restrict__ rs, int n) {
    int t = blockIdx.x * blockDim.x + threadIdx.x;
    if (t < n) rs[t] = rsqrtf(fmaxf((float)cnt[t], 1.0f));
}

// ---------------- exclusive scan (3-phase) over NN ints x 4 rels ----------------
__global__ __launch_bounds__(256) void scan_phase_a(const int* __restrict__ in, int* __restrict__ part) {
    __shared__ int sh[256];
    int rel = blockIdx.y;
    const int* inp = in + rel * NN;
    int tid = threadIdx.x;
    int base = blockIdx.x * 1024 + tid * 4;
    int s = 0;
#pragma unroll
    for (int i = 0; i < 4; i++) { int idx = base + i; if (idx < NN) s += inp[idx]; }
    sh[tid] = s; __syncthreads();
    for (int off = 128; off > 0; off >>= 1) {
        if (tid < off) sh[tid] += sh[tid + off];
        __syncthreads();
    }
    if (tid == 0) part[rel * 128 + blockIdx.x] = sh[0];
}

__global__ void scan_phase_b(int* __restrict__ part) {
    __shared__ int sh[128];
    int rel = blockIdx.x;
    int tid = threadIdx.x;
    int v = (tid < NB_SCAN) ? part[rel * 128 + tid] : 0;
    sh[tid] = v; __syncthreads();
    for (int off = 1; off < 128; off <<= 1) {
        int t = (tid >= off) ? sh[tid - off] : 0;
        __syncthreads();
        sh[tid] += t;
        __syncthreads();
    }
    if (tid < NB_SCAN) part[rel * 128 + tid] = sh[tid] - v;   // exclusive
}

__global__ __launch_bounds__(256) void scan_phase_c(int* __restrict__ cnt, const int* __restrict__ part,
                                                    int* __restrict__ row_ptr, float* __restrict__ rs) {
    __shared__ int sh[256];
    int rel = blockIdx.y;
    int* inp = cnt + rel * NN;
    int* rp = row_ptr + rel * (NN + 1);
    float* rsd = rs + rel * NN;
    int tid = threadIdx.x;
    int base = blockIdx.x * 1024 + tid * 4;
    int v[4]; int s = 0;
#pragma unroll
    for (int i = 0; i < 4; i++) { int idx = base + i; v[i] = (idx < NN) ? inp[idx] : 0; s += v[i]; }
    sh[tid] = s; __syncthreads();
    for (int off = 1; off < 256; off <<= 1) {
        int t = (tid >= off) ? sh[tid - off] : 0;
        __syncthreads();
        sh[tid] += t;
        __syncthreads();
    }
    int excl = sh[tid] - s + part[rel * 128 + blockIdx.x];
#pragma unroll
    for (int i = 0; i < 4; i++) {
        int idx = base + i;
        if (idx < NN) {
            rp[idx] = excl;
            inp[idx] = excl;                     // cursor init
            rsd[idx] = rsqrtf(fmaxf((float)v[i], 1.0f));
            excl += v[i];
        }
    }
    if (blockIdx.x == 0 && tid == 0) rp[NN] = NE;
}

__global__ void fill4_kernel(Ptr4 src, Ptr4 dst, const float* __restrict__ rs_src,
                             int* __restrict__ cursor, int2* __restrict__ edge) {
    int e = blockIdx.x * blockDim.x + threadIdx.x;
    int r = blockIdx.y;
    if (e >= NE) return;
    int s = src.p[r][e], d = dst.p[r][e];
    int p = atomicAdd(&cursor[r * NN + d], 1);
    edge[(size_t)r * NE + p] = make_int2(s, __float_as_int(rs_src[r * NN + s]));
}

// ---------------- weight pack (split hi/lo, MFMA B-fragment order) ----------------
// pack[((nf*4 + ks)*64 + l)*8 + j] = B[ks*32 + (l>>4)*8 + j][nf*16 + (l&15)]
__global__ void pack_all_kernel(PackW pw, ushort* __restrict__ hi, ushort* __restrict__ lo) {
    int tid = blockIdx.x * blockDim.x + threadIdx.x;
    int wi, local, N, trans;
    if (tid < 8 * 16384) { wi = tid >> 14; local = tid & 16383; N = 128; trans = 0; }
    else {
        int t = tid - 8 * 16384;
        if (t >= 49152) return;
        wi = 8; local = t; N = 384; trans = 1;
    }
    int j = local & 7;
    int l = (local >> 3) & 63;
    int ks = (local >> 9) & 3;
    int nf = local >> 11;
    int k = ks * 32 + ((l >> 4) << 3) + j;
    int n = nf * 16 + (l & 15);
    const float* W = pw.w[wi];
    float v = trans ? W[(size_t)n * 128 + k] : W[(size_t)k * N + n];
    size_t d = (size_t)wi * 16384 + local;
    ushort h = f2bf(v);
    hi[d] = h;
    lo[d] = f2bf(v - bf2f(h));
}

// ---------------- fused dual-relation conv (+optional GRU epilogue) ----------------
// 64 dst rows/block, 512 threads. x fp32 (row stride 128 floats).
// Activations single-bf16, weights split hi/lo: D = A*Bh + A*Bl (exact in A).
template <bool GRU_EPI>
__global__ __launch_bounds__(512) void fused_kernel(
    const float* __restrict__ x0, const float* __restrict__ x1,
    Rel A0, Rel B0, Rel A1, Rel B1,
    const ushort* __restrict__ gwh, const ushort* __restrict__ gwl,
    const float* __restrict__ bih, const float* __restrict__ bhh,
    float* __restrict__ C0, float* __restrict__ C1,
    float* __restrict__ H0, float* __restrict__ H1, int n) {
    __shared__ __align__(16) ushort Ah0[64 * 128];
    __shared__ __align__(16) ushort Ah1[64 * 128];
    const Rel A = blockIdx.y ? A1 : A0;
    const Rel B = blockIdx.y ? B1 : B0;
    const int tid = threadIdx.x;
    const int row0 = blockIdx.x * 64;

    // ---- gather BOTH relations into registers (fp32, 2-way unrolled) ----
    const int r = tid >> 3, q = tid & 7;        // 8 threads/row, 16 floats each
    const int d = row0 + r;
    f32x4 gA[4], gB[4];
#pragma unroll
    for (int k = 0; k < 4; k++) { gA[k] = (f32x4)(0.f); gB[k] = (f32x4)(0.f); }
    if (d < n) {
        {
            int j0 = A.rp[d], j1 = A.rp[d + 1];
            int j = j0;
            for (; j + 2 <= j1; j += 2) {
                int2 e0 = A.edge[j], e1 = A.edge[j + 1];
                float s0 = __int_as_float(e0.y), s1 = __int_as_float(e1.y);
                const f32x4* p0 = (const f32x4*)(x0 + (size_t)e0.x * 128 + q * 16);
                const f32x4* p1 = (const f32x4*)(x0 + (size_t)e1.x * 128 + q * 16);
#pragma unroll
                for (int k = 0; k < 4; k++) gA[k] += p0[k] * s0 + p1[k] * s1;
            }
            if (j < j1) {
                int2 e0 = A.edge[j];
                float s0 = __int_as_float(e0.y);
                const f32x4* p0 = (const f32x4*)(x0 + (size_t)e0.x * 128 + q * 16);
#pragma unroll
                for (int k = 0; k < 4; k++) gA[k] += p0[k] * s0;
            }
            float rd = A.rsd[d];
#pragma unroll
            for (int k = 0; k < 4; k++) gA[k] *= rd;
        }
        {
            int j0 = B.rp[d], j1 = B.rp[d + 1];
            int j = j0;
            for (; j + 2 <= j1; j += 2) {
                int2 e0 = B.edge[j], e1 = B.edge[j + 1];
                float s0 = __int_as_float(e0.y), s1 = __int_as_float(e1.y);
                const f32x4* p0 = (const f32x4*)(x1 + (size_t)e0.x * 128 + q * 16);
                const f32x4* p1 = (const f32x4*)(x1 + (size_t)e1.x * 128 + q * 16);
#pragma unroll
                for (int k = 0; k < 4; k++) gB[k] += p0[k] * s0 + p1[k] * s1;
            }
            if (j < j1) {
                int2 e0 = B.edge[j];
                float s0 = __int_as_float(e0.y);
                const f32x4* p0 = (const f32x4*)(x1 + (size_t)e0.x * 128 + q * 16);
#pragma unroll
                for (int k = 0; k < 4; k++) gB[k] += p0[k] * s0;
            }
            float rd = B.rsd[d];
#pragma unroll
            for (int k = 0; k < 4; k++) gB[k] *= rd;
        }
    }

    // ---- stage both relations (single bf16, XOR swizzle), one barrier ----
#pragma unroll
    for (int k = 0; k < 4; k++) {
        int base = (r * 128 + q * 16 + k * 4) ^ ((r & 7) << 3);
        ushort4 h4;
        h4.x = f2bf(gA[k][0]); h4.y = f2bf(gA[k][1]);
        h4.z = f2bf(gA[k][2]); h4.w = f2bf(gA[k][3]);
        *reinterpret_cast<ushort4*>(&Ah0[base]) = h4;
        h4.x = f2bf(gB[k][0]); h4.y = f2bf(gB[k][1]);
        h4.z = f2bf(gB[k][2]); h4.w = f2bf(gB[k][3]);
        *reinterpret_cast<ushort4*>(&Ah1[base]) = h4;
    }
    __syncthreads();

    const int wv = tid >> 6, l = tid & 63;
    const int l15 = l & 15, lh = l >> 4;
    const int rh = wv >> 2, np = wv & 3;

    f32x4 acc[2][2];
#pragma unroll
    for (int m = 0; m < 2; m++)
#pragma unroll
        for (int nfi = 0; nfi < 2; nfi++) acc[m][nfi] = (f32x4)(0.f);

#pragma unroll
    for (int rel = 0; rel < 2; ++rel) {
        const ushort* Ah = rel ? Ah1 : Ah0;
        const ushort* wh = rel ? B.wh : A.wh;
        const ushort* wl = rel ? B.wl : A.wl;
#pragma unroll
        for (int ks = 0; ks < 4; ++ks) {
            bf16x8 aH[2];
#pragma unroll
            for (int m = 0; m < 2; ++m) {
                int row = rh * 32 + m * 16 + l15;
                int idx = (row * 128 + ks * 32 + lh * 8) ^ ((row & 7) << 3);
                aH[m] = *reinterpret_cast<const bf16x8*>(&Ah[idx]);
            }
#pragma unroll
            for (int nfi = 0; nfi < 2; ++nfi) {
                int nf = np * 2 + nfi;
                size_t off = ((size_t)(nf * 4 + ks) * 64 + l) * 8;
                bf16x8 bH = *reinterpret_cast<const bf16x8*>(wh + off);
                bf16x8 bL = *reinterpret_cast<const bf16x8*>(wl + off);
#pragma unroll
                for (int m = 0; m < 2; ++m) {
                    acc[m][nfi] = MFMA(aH[m], bH, acc[m][nfi]);
                    acc[m][nfi] = MFMA(aH[m], bL, acc[m][nfi]);
                }
            }
        }
    }

    if (!GRU_EPI) {
        float* C = blockIdx.y ? C1 : C0;
#pragma unroll
        for (int m = 0; m < 2; ++m) {
            int rbase = row0 + rh * 32 + m * 16 + lh * 4;
#pragma unroll
            for (int nfi = 0; nfi < 2; ++nfi) {
                int c = (np * 2 + nfi) * 16 + l15;
                float bs = A.bias[c] + B.bias[c];
#pragma unroll
                for (int i = 0; i < 4; ++i) {
                    int gr = rbase + i;
                    if (gr < n) C[(size_t)gr * 128 + c] = acc[m][nfi][i] + bs;
                }
            }
        }
        return;
    }

    // ---- phase C: relu(conv+bias) -> single bf16 back into LDS ----
    __syncthreads();                             // all phase-B LDS reads done
#pragma unroll
    for (int m = 0; m < 2; ++m) {
#pragma unroll
        for (int nfi = 0; nfi < 2; ++nfi) {
            int c = (np * 2 + nfi) * 16 + l15;
            float bs = A.bias[c] + B.bias[c];
#pragma unroll
            for (int i = 0; i < 4; ++i) {
                int rr = rh * 32 + m * 16 + lh * 4 + i;
                float v = fmaxf(acc[m][nfi][i] + bs, 0.f);
                int idx = (rr * 128 + c) ^ ((rr & 7) << 3);
                Ah0[idx] = f2bf(v);
            }
        }
    }
    __syncthreads();

    // ---- phase D: gi = relu(x) @ wih^T (3 gates) ----
    f32x4 g3[3][2][2];
#pragma unroll
    for (int g = 0; g < 3; g++)
#pragma unroll
        for (int m = 0; m < 2; m++)
#pragma unroll
            for (int nfi = 0; nfi < 2; nfi++) g3[g][m][nfi] = (f32x4)(0.f);

#pragma unroll
    for (int ks = 0; ks < 4; ++ks) {
        bf16x8 aH[2];
#pragma unroll
        for (int m = 0; m < 2; ++m) {
            int row = rh * 32 + m * 16 + l15;
            int idx = (row * 128 + ks * 32 + lh * 8) ^ ((row & 7) << 3);
            aH[m] = *reinterpret_cast<const bf16x8*>(&Ah0[idx]);
        }
#pragma unroll
        for (int g = 0; g < 3; ++g) {
#pragma unroll
            for (int nfi = 0; nfi < 2; ++nfi) {
                int gnf = g * 8 + np * 2 + nfi;
                size_t off = ((size_t)(gnf * 4 + ks) * 64 + l) * 8;
                bf16x8 bH = *reinterpret_cast<const bf16x8*>(gwh + off);
                bf16x8 bL = *reinterpret_cast<const bf16x8*>(gwl + off);
#pragma unroll
                for (int m = 0; m < 2; ++m) {
                    g3[g][m][nfi] = MFMA(aH[m], bH, g3[g][m][nfi]);
                    g3[g][m][nfi] = MFMA(aH[m], bL, g3[g][m][nfi]);
                }
            }
        }
    }

    // ---- phase E: gates (gh = bhh, h0 = 0), write fp32 h ----
    float* H = blockIdx.y ? H1 : H0;
#pragma unroll
    for (int m = 0; m < 2; ++m) {
        int rbase = row0 + rh * 32 + m * 16 + lh * 4;
#pragma unroll
        for (int nfi = 0; nfi < 2; ++nfi) {
            int c = (np * 2 + nfi) * 16 + l15;
            float b0 = bih[c] + bhh[c];
            float b1 = bih[128 + c] + bhh[128 + c];
            float b2i = bih[256 + c], b2h = bhh[256 + c];
#pragma unroll
            for (int i = 0; i < 4; ++i) {
                int gr = rbase + i;
                if (gr < n) {
                    float rr = fsig(g3[0][m][nfi][i] + b0);
                    float zz = fsig(g3[1][m][nfi][i] + b1);
                    float nn = ftanh(g3[2][m][nfi][i] + b2i + rr * b2h);
                    H[(size_t)gr * 128 + c] = (1.f - zz) * nn;
                }
            }
        }
    }
}

// ---------------- launch ----------------
extern "C" void kernel_launch(void* const* d_in, const int* in_sizes, int n_in,
                              void* d_out, int out_size, void* d_ws, size_t ws_size,
                              hipStream_t stream) {
    const float* feat_user = (const float*)d_in[0];
    const float* feat_item = (const float*)d_in[1];

    // relation order: 0=follows(U->U) 1=buys(U->I) 2=revbuys(I->U) 3=similar(I->I)
    Ptr4 srcs = {{(const int*)d_in[3], (const int*)d_in[9], (const int*)d_in[15], (const int*)d_in[21]}};
    Ptr4 dsts = {{(const int*)d_in[4], (const int*)d_in[10], (const int*)d_in[16], (const int*)d_in[22]}};
    const float* b1[4] = {(const float*)d_in[6],  (const float*)d_in[12], (const float*)d_in[18], (const float*)d_in[24]};
    const float* b2[4] = {(const float*)d_in[8],  (const float*)d_in[14], (const float*)d_in[20], (const float*)d_in[26]};

    PackW pw = {{(const float*)d_in[5], (const float*)d_in[11], (const float*)d_in[17], (const float*)d_in[23],
                 (const float*)d_in[7], (const float*)d_in[13], (const float*)d_in[19], (const float*)d_in[25],
                 (const float*)d_in[27]}};
    const float* bih = (const float*)d_in[29];
    const float* bhh = (const float*)d_in[30];

    // ---- workspace ----
    char* w = (char*)d_ws;
    auto alloc = [&](size_t bytes) { char* r = w; w += (bytes + 255) & ~(size_t)255; return r; };
    int* cnt8         = (int*)alloc(8 * NN * sizeof(int));
    float* rs_src_all = (float*)alloc(4 * NN * sizeof(float));
    float* rs_dst_all = (float*)alloc(4 * NN * sizeof(float));
    int* row_ptr_all  = (int*)alloc(4 * (NN + 1) * sizeof(int));
    int2* edge_all    = (int2*)alloc((size_t)4 * NE * sizeof(int2));
    int* part         = (int*)alloc(4 * 128 * sizeof(int));
    ushort* pkh_all   = (ushort*)alloc((size_t)(8 * 16384 + 49152) * sizeof(ushort));
    ushort* pkl_all   = (ushort*)alloc((size_t)(8 * 16384 + 49152) * sizeof(ushort));
    float* hbuf       = (float*)alloc((size_t)NTOT * 128 * sizeof(float));

    float* outLo = (float*)d_out;
    float* outHi = outLo + (size_t)NU * 128;
    float* hu = hbuf;
    float* hi = hbuf + (size_t)NU * 128;

    const int EB = (NE + 255) / 256;

    // ---- CSR build ----
    hipMemsetAsync(cnt8, 0, 8 * NN * sizeof(int), stream);
    hist8_kernel<<<dim3(EB, 8), 256, 0, stream>>>(srcs, dsts, cnt8);
    scan_phase_a<<<dim3(NB_SCAN, 4), 256, 0, stream>>>(cnt8, part);
    scan_phase_b<<<4, 128, 0, stream>>>(part);
    scan_phase_c<<<dim3(NB_SCAN, 4), 256, 0, stream>>>(cnt8, part, row_ptr_all, rs_dst_all);
    rsqrt_int_kernel<<<(4 * NN + 255) / 256, 256, 0, stream>>>(cnt8 + 4 * NN, rs_src_all, 4 * NN);
    fill4_kernel<<<dim3(EB, 4), 256, 0, stream>>>(srcs, dsts, rs_src_all, cnt8, edge_all);

    // ---- pack weights ----
    pack_all_kernel<<<(8 * 16384 + 49152 + 255) / 256, 256, 0, stream>>>(pw, pkh_all, pkl_all);

    auto mkrel = [&](int r, int wi, const float* bias) {
        Rel R;
        R.rp = row_ptr_all + r * (NN + 1);
        R.edge = edge_all + (size_t)r * NE;
        R.rsd = rs_dst_all + r * NN;
        R.wh = pkh_all + (size_t)wi * 16384;
        R.wl = pkl_all + (size_t)wi * 16384;
        R.bias = bias;
        return R;
    };
    const ushort* gwh = pkh_all + (size_t)8 * 16384;
    const ushort* gwl = pkl_all + (size_t)8 * 16384;
    const int GB = (NN + 63) / 64;   // 1563

    // ---- layer 1 + GRU: feats -> h (fp32), one dispatch ----
    fused_kernel<true><<<dim3(GB, 2), 512, 0, stream>>>(
        feat_user, feat_item,
        mkrel(0, 0, b1[0]), mkrel(2, 2, b1[2]),    // y=0: follows + revbuys -> hu
        mkrel(1, 1, b1[1]), mkrel(3, 3, b1[3]),    // y=1: buys + similar   -> hi
        gwh, gwl, bih, bhh, nullptr, nullptr, hu, hi, NN);

    // ---- layer 2: h -> d_out, one dispatch ----
    fused_kernel<false><<<dim3(GB, 2), 512, 0, stream>>>(
        hu, hi,
        mkrel(0, 4, b2[0]), mkrel(2, 6, b2[2]),    // y=0: ou
        mkrel(1, 5, b2[1]), mkrel(3, 7, b2[3]),    // y=1: oi
        gwh, gwl, bih, bhh, outLo, outHi, nullptr, nullptr, NN);
}